// Round 5
// baseline (464.352 us; speedup 1.0000x reference)
//
#include <hip/hip_runtime.h>
#include <cstddef>
#include <cstdint>

#define DIM   512
#define NSEQ  1024
#define NB    4

typedef unsigned short u16;
typedef short bf16x8 __attribute__((ext_vector_type(8)));
typedef float f32x4  __attribute__((ext_vector_type(4)));

#define MFMA(a, b, c) __builtin_amdgcn_mfma_f32_16x16x32_bf16(a, b, c, 0, 0, 0)

// RNE fp32 -> bf16 split: x ~= hi + lo (error ~2^-18 * |x|)
__device__ inline void split2(float x, u16& h, u16& l) {
  unsigned u = __float_as_uint(x);
  unsigned hb = (u + 0x7fffu + ((u >> 16) & 1u)) >> 16;
  float fh = __uint_as_float(hb << 16);
  float r = x - fh;
  unsigned v = __float_as_uint(r);
  unsigned lb = (v + 0x7fffu + ((v >> 16) & 1u)) >> 16;
  h = (u16)hb; l = (u16)lb;
}

__device__ inline uint2 pack4(const u16 a[4]) {
  return make_uint2((unsigned)a[0] | ((unsigned)a[1] << 16),
                    (unsigned)a[2] | ((unsigned)a[3] << 16));
}

__device__ inline uint4 pack8(const u16 a[8]) {
  return make_uint4((unsigned)a[0] | ((unsigned)a[1] << 16),
                    (unsigned)a[2] | ((unsigned)a[3] << 16),
                    (unsigned)a[4] | ((unsigned)a[5] << 16),
                    (unsigned)a[6] | ((unsigned)a[7] << 16));
}

// fp32 [rows][512] -> u16 [rows][1024] (hi plane | lo plane)
__global__ __launch_bounds__(256) void split_w4(
    const float* __restrict__ w0, const float* __restrict__ w1,
    const float* __restrict__ w2, const float* __restrict__ w3,
    u16* __restrict__ out) {
  const int y = blockIdx.y;
  const float* src = (y == 0) ? w0 : (y == 1) ? w1 : (y == 2) ? w2 : w3;
  u16* o0 = out + (size_t)y * 524288;
  const int e = (blockIdx.x * 256 + threadIdx.x) * 4;
  const int m = e >> 9, c = e & 511;
  const float4 v = *(const float4*)(src + e);
  u16 h[4], l[4];
  split2(v.x, h[0], l[0]); split2(v.y, h[1], l[1]);
  split2(v.z, h[2], l[2]); split2(v.w, h[3], l[3]);
  u16* o = o0 + (size_t)m * 1024 + c;
  *(uint2*)o = pack4(h);
  *(uint2*)(o + 512) = pack4(l);
}

#define GLDS(g, l)                                                        \
  __builtin_amdgcn_global_load_lds(                                       \
      (const __attribute__((address_space(1))) void*)(g),                 \
      (__attribute__((address_space(3))) void*)(l), 16, 0, 0)

// =====================================================================
// Split-bf16 MFMA GEMM body: out = A @ B^T + bias (then *scale).
// A_SPLIT=1: A pre-split u16 [m][1024], staged via GLDS.
// A_SPLIT=0: A fp32 [m][512], split in-kernel during LDS staging.
// OUT_SPLIT=1: out u16 [m][1024] split planes. =0: fp32 [m][512].
// =====================================================================
template <int A_SPLIT, int OUT_SPLIT>
__device__ __forceinline__ void gemm_body(
    u16* __restrict__ Ah, u16* __restrict__ Al,
    u16* __restrict__ Bh, u16* __restrict__ Bl,
    const void* __restrict__ Ap, const u16* __restrict__ B2,
    const float* __restrict__ bias, void* __restrict__ outp,
    float scale, int m0, int n0) {
  const int tid = threadIdx.x;
  const int lane = tid & 63, w = tid >> 6;
  const int wm = (w & 1) * 32, wn = (w >> 1) * 32;

  const int sr  = w * 16 + (lane >> 3);
  const int scg = (lane & 7) ^ (sr & 7);
  const size_t bR = (size_t)(n0 + sr) * 1024 + scg * 8;
  const u16* gBh0 = B2 + bR;        const u16* gBh1 = B2 + bR + 8192;
  const u16* gBl0 = B2 + bR + 512;  const u16* gBl1 = B2 + bR + 8704;
  char* lBh = (char*)Bh + w * 2048; char* lBl = (char*)Bl + w * 2048;

  const u16* gAh0 = nullptr; const u16* gAh1 = nullptr;
  const u16* gAl0 = nullptr; const u16* gAl1 = nullptr;
  char* lAh = (char*)Ah + w * 2048; char* lAl = (char*)Al + w * 2048;
  const float* Af = nullptr;
  int arow = 0, apos0 = 0, apos1 = 0;
  if (A_SPLIT) {
    const size_t aR = (size_t)(m0 + sr) * 1024 + scg * 8;
    gAh0 = (const u16*)Ap + aR; gAh1 = gAh0 + 8192;
    gAl0 = gAh0 + 512;          gAl1 = gAh0 + 8704;
  } else {
    arow = tid >> 2;
    const int acg = tid & 3;
    Af = (const float*)Ap + (size_t)(m0 + arow) * 512 + acg * 8;
    apos0 = (acg ^ (arow & 7)) * 8;
    apos1 = ((acg + 4) ^ (arow & 7)) * 8;
  }

  const int fr = lane & 15, kq = lane >> 4, fx = lane & 7;
  int aoff[2][2], boff[2][2];
#pragma unroll
  for (int s = 0; s < 2; ++s)
#pragma unroll
    for (int t = 0; t < 2; ++t) {
      aoff[s][t] = (wm + t * 16 + fr) * 64 + (((s * 4 + kq) ^ fx)) * 8;
      boff[s][t] = (wn + t * 16 + fr) * 64 + (((s * 4 + kq) ^ fx)) * 8;
    }

  f32x4 acc[2][2] = {};
  for (int k0 = 0; k0 < 512; k0 += 64) {
    float4 f0, f1, f2, f3;
    if (!A_SPLIT) {  // issue fp32 A loads before the barrier (latency overlap)
      f0 = *(const float4*)(Af + k0);
      f1 = *(const float4*)(Af + k0 + 4);
      f2 = *(const float4*)(Af + k0 + 32);
      f3 = *(const float4*)(Af + k0 + 36);
    }
    __syncthreads();
    GLDS(gBh0 + k0, lBh); GLDS(gBh1 + k0, lBh + 1024);
    GLDS(gBl0 + k0, lBl); GLDS(gBl1 + k0, lBl + 1024);
    if (A_SPLIT) {
      GLDS(gAh0 + k0, lAh); GLDS(gAh1 + k0, lAh + 1024);
      GLDS(gAl0 + k0, lAl); GLDS(gAl1 + k0, lAl + 1024);
    } else {
      u16 h8[8], l8[8];
      split2(f0.x, h8[0], l8[0]); split2(f0.y, h8[1], l8[1]);
      split2(f0.z, h8[2], l8[2]); split2(f0.w, h8[3], l8[3]);
      split2(f1.x, h8[4], l8[4]); split2(f1.y, h8[5], l8[5]);
      split2(f1.z, h8[6], l8[6]); split2(f1.w, h8[7], l8[7]);
      *(uint4*)(Ah + arow * 64 + apos0) = pack8(h8);
      *(uint4*)(Al + arow * 64 + apos0) = pack8(l8);
      split2(f2.x, h8[0], l8[0]); split2(f2.y, h8[1], l8[1]);
      split2(f2.z, h8[2], l8[2]); split2(f2.w, h8[3], l8[3]);
      split2(f3.x, h8[4], l8[4]); split2(f3.y, h8[5], l8[5]);
      split2(f3.z, h8[6], l8[6]); split2(f3.w, h8[7], l8[7]);
      *(uint4*)(Ah + arow * 64 + apos1) = pack8(h8);
      *(uint4*)(Al + arow * 64 + apos1) = pack8(l8);
    }
    __syncthreads();
#pragma unroll
    for (int s = 0; s < 2; ++s) {
      bf16x8 ah[2], al[2], bh[2], bl[2];
#pragma unroll
      for (int t = 0; t < 2; ++t) {
        ah[t] = *(const bf16x8*)(Ah + aoff[s][t]);
        al[t] = *(const bf16x8*)(Al + aoff[s][t]);
        bh[t] = *(const bf16x8*)(Bh + boff[s][t]);
        bl[t] = *(const bf16x8*)(Bl + boff[s][t]);
      }
#pragma unroll
      for (int i = 0; i < 2; ++i)
#pragma unroll
        for (int j = 0; j < 2; ++j) {
          acc[i][j] = MFMA(al[i], bh[j], acc[i][j]);
          acc[i][j] = MFMA(ah[i], bl[j], acc[i][j]);
          acc[i][j] = MFMA(ah[i], bh[j], acc[i][j]);
        }
    }
  }

  const int er = (lane >> 4) * 4, ec = lane & 15;
#pragma unroll
  for (int i = 0; i < 2; ++i)
#pragma unroll
    for (int j = 0; j < 2; ++j) {
      const int row = m0 + wm + i * 16 + er;
      const int col = n0 + wn + j * 16 + ec;
      const float bv = bias[col];
#pragma unroll
      for (int r = 0; r < 4; ++r) {
        const float v = (acc[i][j][r] + bv) * scale;
        if (OUT_SPLIT) {
          u16 hh, ll; split2(v, hh, ll);
          u16* o = (u16*)outp;
          o[(size_t)(row + r) * 1024 + col] = hh;
          o[(size_t)(row + r) * 1024 + 512 + col] = ll;
        } else {
          ((float*)outp)[(size_t)(row + r) * 512 + col] = v;
        }
      }
    }
}

// Fused Q/K/V projections: blockIdx.z selects {A, W, bias, out, scale}.
__global__ __launch_bounds__(256) void gemm_qkv(
    const float* __restrict__ xq, const float* __restrict__ xkv,
    const u16* __restrict__ w2, const float* __restrict__ bq,
    const float* __restrict__ bk, const float* __restrict__ bv,
    u16* __restrict__ q2, u16* __restrict__ k2, u16* __restrict__ v2) {
  __shared__ __align__(16) u16 Ah[4096], Al[4096], Bh[4096], Bl[4096];
  const int z = blockIdx.z;
  const float* A = (z == 0) ? xq : xkv;
  const u16* B = w2 + (size_t)z * 524288;
  const float* bias = (z == 0) ? bq : (z == 1) ? bk : bv;
  u16* out = (z == 0) ? q2 : (z == 1) ? k2 : v2;
  const float scale = (z == 0) ? 0.125f : 1.0f;  // fold HD^-0.5 into q
  gemm_body<0, 1>(Ah, Al, Bh, Bl, A, B, bias, out, scale,
                  blockIdx.y * 64, blockIdx.x * 64);
}

// Output projection: A = xa (split from attention), fp32 out.
__global__ __launch_bounds__(256) void gemm_out(
    const u16* __restrict__ xa2, const u16* __restrict__ w2p,
    const float* __restrict__ bp, float* __restrict__ out) {
  __shared__ __align__(16) u16 Ah[4096], Al[4096], Bh[4096], Bl[4096];
  gemm_body<1, 0>(Ah, Al, Bh, Bl, xa2, w2p, bp, out, 1.0f,
                  blockIdx.y * 64, blockIdx.x * 64);
}

// =====================================================================
// Transpose V (split planes) to vt[(b*512+d)][pl*1024 + k].
// =====================================================================
__global__ __launch_bounds__(256) void vtbuild(const u16* __restrict__ v2,
                                               u16* __restrict__ vt) {
  __shared__ u16 Ts[2][64][72];
  const int t = threadIdx.x;
  const int b = blockIdx.z, d0 = blockIdx.y * 64, k0 = blockIdx.x * 64;
  const int r = t >> 3, c8 = (t & 7) * 8;
#pragma unroll
  for (int half = 0; half < 2; ++half) {
    const int kk = r + half * 32;
    const size_t row = (size_t)(b * 1024 + k0 + kk) * 1024;
#pragma unroll
    for (int pl = 0; pl < 2; ++pl)
      *(uint4*)&Ts[pl][kk][c8] = *(const uint4*)(v2 + row + pl * 512 + d0 + c8);
  }
  __syncthreads();
#pragma unroll
  for (int half = 0; half < 2; ++half) {
    const int dd = r + half * 32;
#pragma unroll
    for (int pl = 0; pl < 2; ++pl) {
      u16 tmp[8];
#pragma unroll
      for (int i = 0; i < 8; ++i) tmp[i] = Ts[pl][c8 + i][dd];
      *(uint4*)(vt + (size_t)(b * 512 + d0 + dd) * 2048 + pl * 1024 + k0 + c8) =
          *(uint4*)tmp;
    }
  }
}

// =====================================================================
// MFMA differential flash attention, v2.1 (frame-correct kg merge).
// Grid (32 qtiles, 4 hp, NB*2): blockIdx.z = b*2 + dh (PV d-half split;
// S/softmax duplicated across dh). Block = 512 thr = 8 waves:
// w = kg*4 + h*2 + qs. kg = K-partition (keys kg*512..+512, 16 iters),
// h = head-in-pair, qs = 16-query subtile. Double-buffered K/Vt staging
// via global_load_lds prefetched one tile ahead. kg merge: Ya (Y1/Y3)
// in the wave's own head frame; Yb (Y2 = P2 V1) ALWAYS in head-1's
// frame -> merged with u0/u1 from h1's per-kg (m,l) published in mls.
// =====================================================================
__global__ __launch_bounds__(512) void attn_mfma(
    const u16* __restrict__ q2, const u16* __restrict__ k2,
    const u16* __restrict__ vtg, const int* __restrict__ cq,
    const int* __restrict__ ck, const float* __restrict__ amap,
    const float* __restrict__ lq1, const float* __restrict__ lk1,
    const float* __restrict__ lq2, const float* __restrict__ lk2,
    const float* __restrict__ rpe, u16* __restrict__ xo) {
  __shared__ __align__(16) u16 KsL[2][2][8192];  // [kg][buf][h][pl][32k][64d]
  __shared__ __align__(16) u16 VtL[2][2][4096];  // [kg][buf][h][32d][64ke]
  __shared__ __align__(16) u16 PsL[2][4096];     // [kg][h][32q][64ke]
  __shared__ int2  cks[2][2][32];
  __shared__ float a2s[2][2][16];
  __shared__ float2 mls[2][2][2][16];            // [kg][h][qs][lq] = (m, l)
  __shared__ float y2x[2][64][4];
  __shared__ float lam_s;

  const int tid = threadIdx.x;
  const int lane = tid & 63, w = tid >> 6;
  const int kg = w >> 2, h = (w >> 1) & 1, qs = w & 1;
  const int wl = w & 3;
  const int hp = blockIdx.y;
  const int b = blockIdx.z >> 1, dh = blockIdx.z & 1;
  const int q0 = blockIdx.x * 32;
  const int head = hp + 4 * h;
  const int lq = lane & 15, lg = lane >> 4;
  const int q = qs * 16 + lq;
  const size_t qrow = (size_t)(b * NSEQ + q0 + q);

  // lambda for this head pair (wave 0)
  if (tid < 64) {
    float p1 = lq1[hp * 64 + tid] * lk1[hp * 64 + tid];
    float p2 = lq2[hp * 64 + tid] * lk2[hp * 64 + tid];
#pragma unroll
    for (int m = 32; m >= 1; m >>= 1) {
      p1 += __shfl_xor(p1, m, 64);
      p2 += __shfl_xor(p2, m, 64);
    }
    if (tid == 0) lam_s = __expf(p1) - __expf(p2) + 0.8f;
  }

  const int cq0 = cq[qrow * 2 + 0];
  const int cq1 = cq[qrow * 2 + 1];
  const float alpha = amap[qrow];

  // Q B-frags in registers (q2 pre-scaled by 1/8)
  bf16x8 Qf[2][2];
#pragma unroll
  for (int ks = 0; ks < 2; ++ks)
#pragma unroll
    for (int pl = 0; pl < 2; ++pl)
      Qf[ks][pl] = *(const bf16x8*)(q2 + qrow * 1024 + pl * 512 + head * 64 +
                                    ks * 32 + lg * 8);

  f32x4 Ya[2] = {};   // h0: Y1 dt0,dt1 ; h1: Y3 dt0,dt1
  f32x4 Yb = {};      // h0: Y2 dt0    ; h1: Y2 dt1   (both in h1's frame)
  float m_run = -1e30f, l_run = 0.0f;

  const int sgrp = lane >> 3, scc = (lane & 7) ^ sgrp;

  auto stage = [&](int it, int p) {
    const int k0 = kg * 512 + it * 32;
#pragma unroll
    for (int i = 0; i < 4; ++i) {
      const int c16 = wl * 4 + i;
      const int sh = c16 >> 3, spl = (c16 >> 2) & 1, sub = c16 & 3;
      const int r = sub * 8 + sgrp;
      const u16* src = k2 + (size_t)(b * NSEQ + k0 + r) * 1024 + spl * 512 +
                       (hp + 4 * sh) * 64 + scc * 8;
      GLDS(src, (char*)KsL[kg][p] + c16 * 1024);
    }
#pragma unroll
    for (int i = 0; i < 2; ++i) {
      const int c8 = wl * 2 + i;
      const int sh = c8 >> 2, dg = c8 & 3;
      const int dloc = dg * 8 + sgrp;
      const int spl = scc >> 2, kc = scc & 3;
      const u16* src = vtg +
          (size_t)(b * 512 + (hp + 4 * sh) * 64 + dh * 32 + dloc) * 2048 +
          spl * 1024 + k0 + kc * 8;
      GLDS(src, (char*)VtL[kg][p] + c8 * 1024);
    }
    if (wl == 0 && lane < 32)
      cks[kg][p][lane] = ((const int2*)ck)[b * NSEQ + k0 + lane];
  };

  stage(0, 0);

  for (int it = 0; it < 16; ++it) {
    const int p = it & 1;
    __syncthreads();  // A: tile-it staged; prior-iter LDS reads complete
    if (it + 1 < 16) stage(it + 1, p ^ 1);  // prefetch (drains at next barriers)

    // ---- S^T = K . Q^T (3-term split) ----
    const u16* Kb = KsL[kg][p];
    f32x4 st[2] = {};
#pragma unroll
    for (int kt = 0; kt < 2; ++kt) {
      const int krow = kt * 16 + lq;
      const int rx = krow & 7;
#pragma unroll
      for (int ks = 0; ks < 2; ++ks) {
        const int phys = (ks * 4 + lg) ^ rx;
        const bf16x8 khi = *(const bf16x8*)(Kb + ((h * 2 + 0) * 32 + krow) * 64 + phys * 8);
        const bf16x8 klo = *(const bf16x8*)(Kb + ((h * 2 + 1) * 32 + krow) * 64 + phys * 8);
        st[kt] = MFMA(khi, Qf[ks][1], st[kt]);
        st[kt] = MFMA(klo, Qf[ks][0], st[kt]);
        st[kt] = MFMA(khi, Qf[ks][0], st[kt]);
      }
    }

    // ---- RPE gather + online softmax (q = lane col, k = regs) ----
    float sv[2][4];
    float mx = -1e30f;
#pragma unroll
    for (int kt = 0; kt < 2; ++kt)
#pragma unroll
      for (int r = 0; r < 4; ++r) {
        const int k = kt * 16 + lg * 4 + r;
        const int2 c = cks[kg][p][k];
        const int r0 = min(max(cq0 - c.x + 128, 0), 256);
        const int r1 = min(max(cq1 - c.y + 128, 0), 256);
        const float s = st[kt][r] + rpe[(r0 * 257 + r1) * 8 + head];
        sv[kt][r] = s;
        mx = fmaxf(mx, s);
      }
    mx = fmaxf(mx, __shfl_xor(mx, 16, 64));
    mx = fmaxf(mx, __shfl_xor(mx, 32, 64));
    const float mnew = fmaxf(m_run, mx);
    const float a = __expf(m_run - mnew);
    m_run = mnew;
    float pv[2][4], ps = 0.0f;
#pragma unroll
    for (int kt = 0; kt < 2; ++kt)
#pragma unroll
      for (int r = 0; r < 4; ++r) {
        pv[kt][r] = __expf(sv[kt][r] - mnew);
        ps += pv[kt][r];
      }
    ps += __shfl_xor(ps, 16, 64);
    ps += __shfl_xor(ps, 32, 64);
    l_run = l_run * a + ps;
    Ya[0] *= a; Ya[1] *= a;
    if (h == 1) {
      Yb *= a;
      if (lane < 16) a2s[kg][qs][lane] = a;
    }

    // ---- write split-bf16 P to LDS ----
    u16* Pb = PsL[kg];
#pragma unroll
    for (int kt = 0; kt < 2; ++kt) {
      u16 hh[4], ll[4];
#pragma unroll
      for (int r = 0; r < 4; ++r) split2(pv[kt][r], hh[r], ll[r]);
      const int kc = kt * 2 + (lg >> 1);
      const int base = (h * 32 + q) * 64 + (lg & 1) * 4;
      *(uint2*)(Pb + base + ((kc ^ (q & 7)) * 8)) = pack4(hh);
      *(uint2*)(Pb + base + (((4 + kc) ^ (q & 7)) * 8)) = pack4(ll);
    }
    __syncthreads();  // C: P visible (prefetch mostly landed by now)

    // ---- PV (d-half: 2 dt of 16) ----
    const u16* Vb = VtL[kg][p];
    const int qx = q & 7;
    const bf16x8 p2h = *(const bf16x8*)(Pb + (32 + q) * 64 + ((0 * 4 + lg) ^ qx) * 8);
    const bf16x8 p2l = *(const bf16x8*)(Pb + (32 + q) * 64 + ((1 * 4 + lg) ^ qx) * 8);
    if (h == 0) {
      Yb *= a2s[kg][qs][lq];
      const bf16x8 p1h = *(const bf16x8*)(Pb + q * 64 + ((0 * 4 + lg) ^ qx) * 8);
      const bf16x8 p1l = *(const bf16x8*)(Pb + q * 64 + ((1 * 4 + lg) ^ qx) * 8);
#pragma unroll
      for (int dt = 0; dt < 2; ++dt) {
        const int dl = dt * 16 + lq;
        const bf16x8 vh = *(const bf16x8*)(Vb + dl * 64 + ((0 * 4 + lg) ^ (dl & 7)) * 8);
        const bf16x8 vl = *(const bf16x8*)(Vb + dl * 64 + ((1 * 4 + lg) ^ (dl & 7)) * 8);
        Ya[dt] = MFMA(vh, p1l, Ya[dt]);
        Ya[dt] = MFMA(vl, p1h, Ya[dt]);
        Ya[dt] = MFMA(vh, p1h, Ya[dt]);
        if (dt == 0) {
          Yb = MFMA(vh, p2l, Yb);
          Yb = MFMA(vl, p2h, Yb);
          Yb = MFMA(vh, p2h, Yb);
        }
      }
    } else {
#pragma unroll
      for (int dt = 0; dt < 2; ++dt) {
        const int dl = dt * 16 + lq;
        const bf16x8 vh = *(const bf16x8*)(Vb + (32 + dl) * 64 + ((0 * 4 + lg) ^ (dl & 7)) * 8);
        const bf16x8 vl = *(const bf16x8*)(Vb + (32 + dl) * 64 + ((1 * 4 + lg) ^ (dl & 7)) * 8);
        Ya[dt] = MFMA(vh, p2l, Ya[dt]);
        Ya[dt] = MFMA(vl, p2h, Ya[dt]);
        Ya[dt] = MFMA(vh, p2h, Ya[dt]);
      }
      const int dl = 16 + lq;  // Y2 dt1 uses V1
      const bf16x8 vh = *(const bf16x8*)(Vb + dl * 64 + ((0 * 4 + lg) ^ (dl & 7)) * 8);
      const bf16x8 vl = *(const bf16x8*)(Vb + dl * 64 + ((1 * 4 + lg) ^ (dl & 7)) * 8);
      Yb = MFMA(vh, p2l, Yb);
      Yb = MFMA(vl, p2h, Yb);
      Yb = MFMA(vh, p2h, Yb);
    }
  }

  // ---- merge kg partials (frame-correct) ----
  float* mY = (float*)KsL;   // [wl][64 lanes][12] fp32 scratch
  __syncthreads();
  if (lane < 16) mls[kg][h][qs][lane] = make_float2(m_run, l_run);
  if (kg == 1) {
#pragma unroll
    for (int dt = 0; dt < 2; ++dt)
#pragma unroll
      for (int e = 0; e < 4; ++e) mY[(wl * 64 + lane) * 12 + dt * 4 + e] = Ya[dt][e];
#pragma unroll
    for (int e = 0; e < 4; ++e) mY[(wl * 64 + lane) * 12 + 8 + e] = Yb[e];
  }
  __syncthreads();
  float l_tot = l_run, l_tot2 = 0.0f;
  if (kg == 0) {
    // own-head frame for Ya (Y1 or Y3)
    const float2 own1 = mls[1][h][qs][lq];
    const float mm = fmaxf(m_run, own1.x);
    const float s0 = __expf(m_run - mm);
    const float s1 = __expf(own1.x - mm);
    l_tot = l_run * s0 + own1.y * s1;
    // head-1 frame for Yb (Y2) and its denominator
    const float2 t0 = mls[0][1][qs][lq];
    const float2 t1 = mls[1][1][qs][lq];
    const float mm2 = fmaxf(t0.x, t1.x);
    const float u0 = __expf(t0.x - mm2);
    const float u1 = __expf(t1.x - mm2);
    l_tot2 = t0.y * u0 + t1.y * u1;
    const float* src = mY + (wl * 64 + lane) * 12;
#pragma unroll
    for (int dt = 0; dt < 2; ++dt)
#pragma unroll
      for (int e = 0; e < 4; ++e) Ya[dt][e] = Ya[dt][e] * s0 + src[dt * 4 + e] * s1;
#pragma unroll
    for (int e = 0; e < 4; ++e) Yb[e] = Yb[e] * u0 + src[8 + e] * u1;
  }

  // ---- epilogue (kg0 only): exchange h1's Y2 half, combine, emit ----
  if (kg == 0 && h == 1) {
#pragma unroll
    for (int e = 0; e < 4; ++e) y2x[qs][lane][e] = Yb[e];
    const float inv2 = 1.0f / l_tot;
#pragma unroll
    for (int dt = 0; dt < 2; ++dt) {
      u16 hh[4], ll[4];
#pragma unroll
      for (int r = 0; r < 4; ++r) split2(Ya[dt][r] * inv2, hh[r], ll[r]);
      u16* o = xo + qrow * 1024 + (hp + 4) * 64 + dh * 32 + dt * 16 + lg * 4;
      *(uint2*)o = pack4(hh);
      *(uint2*)(o + 512) = pack4(ll);
    }
  }
  __syncthreads();
  if (kg == 0 && h == 0) {
    const float inv1 = 1.0f / l_tot;
    const float inv2 = 1.0f / l_tot2;
    const float lam = lam_s;
    const float c1 = (1.0f + alpha) * inv1;
    const float c2 = alpha * lam * inv2;
#pragma unroll
    for (int dt = 0; dt < 2; ++dt) {
      u16 hh[4], ll[4];
#pragma unroll
      for (int r = 0; r < 4; ++r) {
        const float y2 = (dt == 0) ? Yb[r] : y2x[qs][lane][r];
        split2(c1 * Ya[dt][r] - c2 * y2, hh[r], ll[r]);
      }
      u16* o = xo + qrow * 1024 + hp * 64 + dh * 32 + dt * 16 + lg * 4;
      *(uint2*)o = pack4(hh);
      *(uint2*)(o + 512) = pack4(ll);
    }
  }
}

// =====================================================================
extern "C" void kernel_launch(void* const* d_in, const int* in_sizes, int n_in,
                              void* d_out, int out_size, void* d_ws, size_t ws_size,
                              hipStream_t stream) {
  const float* x_q   = (const float*)d_in[0];
  const float* x_kv  = (const float*)d_in[1];
  const int*   c_q   = (const int*)d_in[2];
  const int*   c_k   = (const int*)d_in[3];
  const float* alpha = (const float*)d_in[4];
  const float* Wq    = (const float*)d_in[5];
  const float* bq    = (const float*)d_in[6];
  const float* Wk    = (const float*)d_in[7];
  const float* bk    = (const float*)d_in[8];
  const float* Wv    = (const float*)d_in[9];
  const float* bv    = (const float*)d_in[10];
  const float* lq1   = (const float*)d_in[11];
  const float* lk1   = (const float*)d_in[12];
  const float* lq2   = (const float*)d_in[13];
  const float* lk2   = (const float*)d_in[14];
  const float* rpe   = (const float*)d_in[15];
  const float* Wp    = (const float*)d_in[16];
  const float* bp    = (const float*)d_in[17];

  // ws (28 MB): w2[0,4) | q2[4,12) | k2[12,20) | vbuf[20,28) (v2 then xa)
  // d_out (8 MB): vt during attention, then the final output.
  u16* w2   = (u16*)d_ws;
  u16* q2   = (u16*)((char*)d_ws + (4u << 20));
  u16* k2   = (u16*)((char*)d_ws + (12u << 20));
  u16* vbuf = (u16*)((char*)d_ws + (20u << 20));
  u16* vt   = (u16*)d_out;

  split_w4<<<dim3(256, 4), 256, 0, stream>>>(Wq, Wk, Wv, Wp, w2);
  gemm_qkv<<<dim3(8, 64, 3), 256, 0, stream>>>(x_q, x_kv, w2, bq, bk, bv,
                                               q2, k2, vbuf);
  vtbuild<<<dim3(16, 8, 4), 256, 0, stream>>>(vbuf, vt);
  attn_mfma<<<dim3(32, 4, NB * 2), 512, 0, stream>>>(
      q2, k2, vt, c_q, c_k, alpha, lq1, lk1, lq2, lk2, rpe, vbuf);
  gemm_out<<<dim3(8, 64), 256, 0, stream>>>(vbuf, w2 + 3 * 524288, bp,
                                            (float*)d_out);
}

// Round 6
// 307.455 us; speedup vs baseline: 1.5103x; 1.5103x over previous
//
#include <hip/hip_runtime.h>
#include <cstddef>
#include <cstdint>

#define DIM   512
#define NSEQ  1024
#define NB    4

typedef unsigned short u16;
typedef short bf16x8 __attribute__((ext_vector_type(8)));
typedef float f32x4  __attribute__((ext_vector_type(4)));

#define MFMA(a, b, c) __builtin_amdgcn_mfma_f32_16x16x32_bf16(a, b, c, 0, 0, 0)

// RNE fp32 -> bf16 split: x ~= hi + lo (error ~2^-18 * |x|)
__device__ inline void split2(float x, u16& h, u16& l) {
  unsigned u = __float_as_uint(x);
  unsigned hb = (u + 0x7fffu + ((u >> 16) & 1u)) >> 16;
  float fh = __uint_as_float(hb << 16);
  float r = x - fh;
  unsigned v = __float_as_uint(r);
  unsigned lb = (v + 0x7fffu + ((v >> 16) & 1u)) >> 16;
  h = (u16)hb; l = (u16)lb;
}

__device__ inline uint2 pack4(const u16 a[4]) {
  return make_uint2((unsigned)a[0] | ((unsigned)a[1] << 16),
                    (unsigned)a[2] | ((unsigned)a[3] << 16));
}

__device__ inline uint4 pack8(const u16 a[8]) {
  return make_uint4((unsigned)a[0] | ((unsigned)a[1] << 16),
                    (unsigned)a[2] | ((unsigned)a[3] << 16),
                    (unsigned)a[4] | ((unsigned)a[5] << 16),
                    (unsigned)a[6] | ((unsigned)a[7] << 16));
}

// fp32 [rows][512] -> u16 [rows][1024] (hi plane | lo plane)
__global__ __launch_bounds__(256) void split_w4(
    const float* __restrict__ w0, const float* __restrict__ w1,
    const float* __restrict__ w2, const float* __restrict__ w3,
    u16* __restrict__ out) {
  const int y = blockIdx.y;
  const float* src = (y == 0) ? w0 : (y == 1) ? w1 : (y == 2) ? w2 : w3;
  u16* o0 = out + (size_t)y * 524288;
  const int e = (blockIdx.x * 256 + threadIdx.x) * 4;
  const int m = e >> 9, c = e & 511;
  const float4 v = *(const float4*)(src + e);
  u16 h[4], l[4];
  split2(v.x, h[0], l[0]); split2(v.y, h[1], l[1]);
  split2(v.z, h[2], l[2]); split2(v.w, h[3], l[3]);
  u16* o = o0 + (size_t)m * 1024 + c;
  *(uint2*)o = pack4(h);
  *(uint2*)(o + 512) = pack4(l);
}

#define GLDS(g, l)                                                        \
  __builtin_amdgcn_global_load_lds(                                       \
      (const __attribute__((address_space(1))) void*)(g),                 \
      (__attribute__((address_space(3))) void*)(l), 16, 0, 0)

// =====================================================================
// Split-bf16 MFMA GEMM body: out = A @ B^T + bias (then *scale).
// (unchanged from round 2/5 — validated)
// =====================================================================
template <int A_SPLIT, int OUT_SPLIT>
__device__ __forceinline__ void gemm_body(
    u16* __restrict__ Ah, u16* __restrict__ Al,
    u16* __restrict__ Bh, u16* __restrict__ Bl,
    const void* __restrict__ Ap, const u16* __restrict__ B2,
    const float* __restrict__ bias, void* __restrict__ outp,
    float scale, int m0, int n0) {
  const int tid = threadIdx.x;
  const int lane = tid & 63, w = tid >> 6;
  const int wm = (w & 1) * 32, wn = (w >> 1) * 32;

  const int sr  = w * 16 + (lane >> 3);
  const int scg = (lane & 7) ^ (sr & 7);
  const size_t bR = (size_t)(n0 + sr) * 1024 + scg * 8;
  const u16* gBh0 = B2 + bR;        const u16* gBh1 = B2 + bR + 8192;
  const u16* gBl0 = B2 + bR + 512;  const u16* gBl1 = B2 + bR + 8704;
  char* lBh = (char*)Bh + w * 2048; char* lBl = (char*)Bl + w * 2048;

  const u16* gAh0 = nullptr; const u16* gAh1 = nullptr;
  const u16* gAl0 = nullptr; const u16* gAl1 = nullptr;
  char* lAh = (char*)Ah + w * 2048; char* lAl = (char*)Al + w * 2048;
  const float* Af = nullptr;
  int arow = 0, apos0 = 0, apos1 = 0;
  if (A_SPLIT) {
    const size_t aR = (size_t)(m0 + sr) * 1024 + scg * 8;
    gAh0 = (const u16*)Ap + aR; gAh1 = gAh0 + 8192;
    gAl0 = gAh0 + 512;          gAl1 = gAh0 + 8704;
  } else {
    arow = tid >> 2;
    const int acg = tid & 3;
    Af = (const float*)Ap + (size_t)(m0 + arow) * 512 + acg * 8;
    apos0 = (acg ^ (arow & 7)) * 8;
    apos1 = ((acg + 4) ^ (arow & 7)) * 8;
  }

  const int fr = lane & 15, kq = lane >> 4, fx = lane & 7;
  int aoff[2][2], boff[2][2];
#pragma unroll
  for (int s = 0; s < 2; ++s)
#pragma unroll
    for (int t = 0; t < 2; ++t) {
      aoff[s][t] = (wm + t * 16 + fr) * 64 + (((s * 4 + kq) ^ fx)) * 8;
      boff[s][t] = (wn + t * 16 + fr) * 64 + (((s * 4 + kq) ^ fx)) * 8;
    }

  f32x4 acc[2][2] = {};
  for (int k0 = 0; k0 < 512; k0 += 64) {
    float4 f0, f1, f2, f3;
    if (!A_SPLIT) {
      f0 = *(const float4*)(Af + k0);
      f1 = *(const float4*)(Af + k0 + 4);
      f2 = *(const float4*)(Af + k0 + 32);
      f3 = *(const float4*)(Af + k0 + 36);
    }
    __syncthreads();
    GLDS(gBh0 + k0, lBh); GLDS(gBh1 + k0, lBh + 1024);
    GLDS(gBl0 + k0, lBl); GLDS(gBl1 + k0, lBl + 1024);
    if (A_SPLIT) {
      GLDS(gAh0 + k0, lAh); GLDS(gAh1 + k0, lAh + 1024);
      GLDS(gAl0 + k0, lAl); GLDS(gAl1 + k0, lAl + 1024);
    } else {
      u16 h8[8], l8[8];
      split2(f0.x, h8[0], l8[0]); split2(f0.y, h8[1], l8[1]);
      split2(f0.z, h8[2], l8[2]); split2(f0.w, h8[3], l8[3]);
      split2(f1.x, h8[4], l8[4]); split2(f1.y, h8[5], l8[5]);
      split2(f1.z, h8[6], l8[6]); split2(f1.w, h8[7], l8[7]);
      *(uint4*)(Ah + arow * 64 + apos0) = pack8(h8);
      *(uint4*)(Al + arow * 64 + apos0) = pack8(l8);
      split2(f2.x, h8[0], l8[0]); split2(f2.y, h8[1], l8[1]);
      split2(f2.z, h8[2], l8[2]); split2(f2.w, h8[3], l8[3]);
      split2(f3.x, h8[4], l8[4]); split2(f3.y, h8[5], l8[5]);
      split2(f3.z, h8[6], l8[6]); split2(f3.w, h8[7], l8[7]);
      *(uint4*)(Ah + arow * 64 + apos1) = pack8(h8);
      *(uint4*)(Al + arow * 64 + apos1) = pack8(l8);
    }
    __syncthreads();
#pragma unroll
    for (int s = 0; s < 2; ++s) {
      bf16x8 ah[2], al[2], bh[2], bl[2];
#pragma unroll
      for (int t = 0; t < 2; ++t) {
        ah[t] = *(const bf16x8*)(Ah + aoff[s][t]);
        al[t] = *(const bf16x8*)(Al + aoff[s][t]);
        bh[t] = *(const bf16x8*)(Bh + boff[s][t]);
        bl[t] = *(const bf16x8*)(Bl + boff[s][t]);
      }
#pragma unroll
      for (int i = 0; i < 2; ++i)
#pragma unroll
        for (int j = 0; j < 2; ++j) {
          acc[i][j] = MFMA(al[i], bh[j], acc[i][j]);
          acc[i][j] = MFMA(ah[i], bl[j], acc[i][j]);
          acc[i][j] = MFMA(ah[i], bh[j], acc[i][j]);
        }
    }
  }

  const int er = (lane >> 4) * 4, ec = lane & 15;
#pragma unroll
  for (int i = 0; i < 2; ++i)
#pragma unroll
    for (int j = 0; j < 2; ++j) {
      const int row = m0 + wm + i * 16 + er;
      const int col = n0 + wn + j * 16 + ec;
      const float bv = bias[col];
#pragma unroll
      for (int r = 0; r < 4; ++r) {
        const float v = (acc[i][j][r] + bv) * scale;
        if (OUT_SPLIT) {
          u16 hh, ll; split2(v, hh, ll);
          u16* o = (u16*)outp;
          o[(size_t)(row + r) * 1024 + col] = hh;
          o[(size_t)(row + r) * 1024 + 512 + col] = ll;
        } else {
          ((float*)outp)[(size_t)(row + r) * 512 + col] = v;
        }
      }
    }
}

__global__ __launch_bounds__(256) void gemm_qkv(
    const float* __restrict__ xq, const float* __restrict__ xkv,
    const u16* __restrict__ w2, const float* __restrict__ bq,
    const float* __restrict__ bk, const float* __restrict__ bv,
    u16* __restrict__ q2, u16* __restrict__ k2, u16* __restrict__ v2) {
  __shared__ __align__(16) u16 Ah[4096], Al[4096], Bh[4096], Bl[4096];
  const int z = blockIdx.z;
  const float* A = (z == 0) ? xq : xkv;
  const u16* B = w2 + (size_t)z * 524288;
  const float* bias = (z == 0) ? bq : (z == 1) ? bk : bv;
  u16* out = (z == 0) ? q2 : (z == 1) ? k2 : v2;
  const float scale = (z == 0) ? 0.125f : 1.0f;
  gemm_body<0, 1>(Ah, Al, Bh, Bl, A, B, bias, out, scale,
                  blockIdx.y * 64, blockIdx.x * 64);
}

__global__ __launch_bounds__(256) void gemm_out(
    const u16* __restrict__ xa2, const u16* __restrict__ w2p,
    const float* __restrict__ bp, float* __restrict__ out) {
  __shared__ __align__(16) u16 Ah[4096], Al[4096], Bh[4096], Bl[4096];
  gemm_body<1, 0>(Ah, Al, Bh, Bl, xa2, w2p, bp, out, 1.0f,
                  blockIdx.y * 64, blockIdx.x * 64);
}

// =====================================================================
// Transpose V (split planes) to vt[(b*512+d)][pl*1024 + k].
// =====================================================================
__global__ __launch_bounds__(256) void vtbuild(const u16* __restrict__ v2,
                                               u16* __restrict__ vt) {
  __shared__ u16 Ts[2][64][72];
  const int t = threadIdx.x;
  const int b = blockIdx.z, d0 = blockIdx.y * 64, k0 = blockIdx.x * 64;
  const int r = t >> 3, c8 = (t & 7) * 8;
#pragma unroll
  for (int half = 0; half < 2; ++half) {
    const int kk = r + half * 32;
    const size_t row = (size_t)(b * 1024 + k0 + kk) * 1024;
#pragma unroll
    for (int pl = 0; pl < 2; ++pl)
      *(uint4*)&Ts[pl][kk][c8] = *(const uint4*)(v2 + row + pl * 512 + d0 + c8);
  }
  __syncthreads();
#pragma unroll
  for (int half = 0; half < 2; ++half) {
    const int dd = r + half * 32;
#pragma unroll
    for (int pl = 0; pl < 2; ++pl) {
      u16 tmp[8];
#pragma unroll
      for (int i = 0; i < 8; ++i) tmp[i] = Ts[pl][c8 + i][dd];
      *(uint4*)(vt + (size_t)(b * 512 + d0 + dd) * 2048 + pl * 1024 + k0 + c8) =
          *(uint4*)tmp;
    }
  }
}

// =====================================================================
// MFMA differential flash attention, v3: one barrier per K-iteration.
// Grid (32 qtiles, 4 hp, NB), block 256 = 4 waves (h, qs). Each wave:
// 16 q, one head, full 64 d, all 1024 keys in 32-key tiles.
// Double-buffered K/Vt staged via global_load_lds issued immediately
// after the (single) barrier -> a full compute phase in flight before
// the next barrier's vmcnt drain. P stays in REGISTERS: D-layout ->
// B-operand transform via 16 __shfl (no P-LDS, no second barrier).
// h0 waves: Y1 = P1V1. h1 waves: Y2 = P2V1, Y3 = P2V2 (own frame, own
// rescale). RPE gather software-pipelined: ck coords 2 tiles ahead,
// rpe values 1 tile ahead (register pipeline, no LDS).
// Epilogue: h1 publishes Y2 + l2 via LDS once; h0 combines lam/alpha.
// =====================================================================
__global__ __launch_bounds__(256) void attn_mfma(
    const u16* __restrict__ q2, const u16* __restrict__ k2,
    const u16* __restrict__ vtg, const int* __restrict__ cq,
    const int* __restrict__ ck, const float* __restrict__ amap,
    const float* __restrict__ lq1, const float* __restrict__ lk1,
    const float* __restrict__ lq2, const float* __restrict__ lk2,
    const float* __restrict__ rpe, u16* __restrict__ xo) {
  __shared__ __align__(16) u16 KsL[2][8192];  // [buf][(h*2+pl)*32+k][64 d-entries]
  __shared__ __align__(16) u16 VtL[2][8192];  // [buf][h*64+d][hi32k|lo32k]
  __shared__ float lam_s;

  const int tid = threadIdx.x;
  const int lane = tid & 63, w = tid >> 6;
  const int h = w >> 1, qs = w & 1;
  const int hp = blockIdx.y, b = blockIdx.z;
  const int q0 = blockIdx.x * 32;
  const int head = hp + 4 * h;
  const int lq = lane & 15, lg = lane >> 4;
  const int q = qs * 16 + lq;
  const size_t qrow = (size_t)(b * NSEQ + q0 + q);

  // lambda for this head pair (wave 0)
  if (tid < 64) {
    float p1 = lq1[hp * 64 + tid] * lk1[hp * 64 + tid];
    float p2 = lq2[hp * 64 + tid] * lk2[hp * 64 + tid];
#pragma unroll
    for (int m = 32; m >= 1; m >>= 1) {
      p1 += __shfl_xor(p1, m, 64);
      p2 += __shfl_xor(p2, m, 64);
    }
    if (tid == 0) lam_s = __expf(p1) - __expf(p2) + 0.8f;
  }

  const int cq0 = cq[qrow * 2 + 0];
  const int cq1 = cq[qrow * 2 + 1];
  const float alpha = amap[qrow];

  // Q B-frags in registers (q2 pre-scaled by 1/8)
  bf16x8 Qf[2][2];
#pragma unroll
  for (int ks = 0; ks < 2; ++ks)
#pragma unroll
    for (int pl = 0; pl < 2; ++pl)
      Qf[ks][pl] = *(const bf16x8*)(q2 + qrow * 1024 + pl * 512 + head * 64 +
                                    ks * 32 + lg * 8);

  f32x4 Ya[4] = {};  // h0: Y1 ; h1: Y3
  f32x4 Yb[4] = {};  // h1: Y2 (h0 unused)
  float m_run = -1e30f, l_run = 0.0f;

  const int sgrp = lane >> 3, scc = (lane & 7) ^ sgrp;
  const int cw = w * 4;

  auto stage = [&](int it, int p) {
#pragma unroll
    for (int i = 0; i < 4; ++i) {
      const int c = cw + i;
      const int sh = c >> 3, spl = (c >> 2) & 1, sub = c & 3;
      const int r = sub * 8 + sgrp;
      const u16* src = k2 + (size_t)(b * NSEQ + it * 32 + r) * 1024 + spl * 512 +
                       (hp + 4 * sh) * 64 + scc * 8;
      GLDS(src, (char*)KsL[p] + c * 1024);
    }
#pragma unroll
    for (int i = 0; i < 4; ++i) {
      const int c = cw + i;
      const int sh = c >> 3, dg = c & 7;
      const int d = dg * 8 + sgrp;
      const int spl = scc >> 2, kc = scc & 3;
      const u16* src = vtg + (size_t)(b * 512 + (hp + 4 * sh) * 64 + d) * 2048 +
                       spl * 1024 + it * 32 + kc * 8;
      GLDS(src, (char*)VtL[p] + c * 1024);
    }
  };

  // RPE register pipeline: coords 2 tiles ahead, values 1 tile ahead.
  const int2* ck2 = (const int2*)ck;
  int2 ncA[8], ncB[8];
  float rv[8];
  auto loadNC = [&](int it, int2* nc) {
    const int base = b * NSEQ + it * 32 + lg * 4;
#pragma unroll
    for (int kt = 0; kt < 2; ++kt)
#pragma unroll
      for (int r = 0; r < 4; ++r) nc[kt * 4 + r] = ck2[base + kt * 16 + r];
  };
  auto loadRPE = [&](const int2* nc, float* dst) {
#pragma unroll
    for (int e = 0; e < 8; ++e) {
      const int r0 = min(max(cq0 - nc[e].x + 128, 0), 256);
      const int r1 = min(max(cq1 - nc[e].y + 128, 0), 256);
      dst[e] = rpe[(r0 * 257 + r1) * 8 + head];
    }
  };

  stage(0, 0);
  loadNC(0, ncA);
  loadRPE(ncA, rv);   // serial once at startup
  loadNC(1, ncB);

  for (int it = 0; it < 32; ++it) {
    const int p = it & 1;
    __syncthreads();  // drains staging of tile it (in flight a full iter)
    if (it + 1 < 32) stage(it + 1, p ^ 1);

    // ---- S^T = K . Q^T (3-term split) ----
    const u16* Kb = KsL[p];
    f32x4 st[2] = {};
#pragma unroll
    for (int kt = 0; kt < 2; ++kt) {
      const int krow = kt * 16 + lq;
      const int rx = krow & 7;
#pragma unroll
      for (int ks = 0; ks < 2; ++ks) {
        const int phys = (ks * 4 + lg) ^ rx;
        const bf16x8 khi = *(const bf16x8*)(Kb + ((h * 2 + 0) * 32 + krow) * 64 + phys * 8);
        const bf16x8 klo = *(const bf16x8*)(Kb + ((h * 2 + 1) * 32 + krow) * 64 + phys * 8);
        st[kt] = MFMA(khi, Qf[ks][1], st[kt]);
        st[kt] = MFMA(klo, Qf[ks][0], st[kt]);
        st[kt] = MFMA(khi, Qf[ks][0], st[kt]);
      }
    }

    // ---- online softmax with prefetched rpe (q = lane col, k = regs) ----
    float sv[2][4];
    float mx = -1e30f;
#pragma unroll
    for (int kt = 0; kt < 2; ++kt)
#pragma unroll
      for (int r = 0; r < 4; ++r) {
        const float s = st[kt][r] + rv[kt * 4 + r];
        sv[kt][r] = s;
        mx = fmaxf(mx, s);
      }
    mx = fmaxf(mx, __shfl_xor(mx, 16, 64));
    mx = fmaxf(mx, __shfl_xor(mx, 32, 64));
    const float mnew = fmaxf(m_run, mx);
    const float a = __expf(m_run - mnew);
    m_run = mnew;
    float pr[2][4], ps = 0.0f;
#pragma unroll
    for (int kt = 0; kt < 2; ++kt)
#pragma unroll
      for (int r = 0; r < 4; ++r) {
        pr[kt][r] = __expf(sv[kt][r] - mnew);
        ps += pr[kt][r];
      }
    ps += __shfl_xor(ps, 16, 64);
    ps += __shfl_xor(ps, 32, 64);
    l_run = l_run * a + ps;
#pragma unroll
    for (int dt = 0; dt < 4; ++dt) Ya[dt] *= a;
    if (h == 1) {
#pragma unroll
      for (int dt = 0; dt < 4; ++dt) Yb[dt] *= a;
    }

    // ---- refill rpe pipeline (consumed above; next values in flight) ----
    {
      const int itn = (it + 2 > 31) ? 31 : it + 2;
      if ((it & 1) == 0) { loadRPE(ncB, rv); loadNC(itn, ncA); }
      else               { loadRPE(ncA, rv); loadNC(itn, ncB); }
    }

    // ---- P: D-layout -> B-operand frag via shuffles, split-bf16 ----
    // lane needs P[k=8*lg+j][lq]; sources: lanes lq+32*(lg&1) (+16), tile lg>=2.
    const int srcA = lq + ((lg & 1) << 5);
    float pj[8];
#pragma unroll
    for (int r = 0; r < 4; ++r) {
      const float t0 = __shfl(pr[0][r], srcA);
      const float t1 = __shfl(pr[1][r], srcA);
      pj[r] = (lg >= 2) ? t1 : t0;
      const float u0 = __shfl(pr[0][r], srcA + 16);
      const float u1 = __shfl(pr[1][r], srcA + 16);
      pj[4 + r] = (lg >= 2) ? u1 : u0;
    }
    u16 phh[8], pll[8];
#pragma unroll
    for (int e = 0; e < 8; ++e) split2(pj[e], phh[e], pll[e]);
    const uint4 Hu = pack8(phh), Lu = pack8(pll);
    bf16x8 pbh, pbl;
    __builtin_memcpy(&pbh, &Hu, 16);
    __builtin_memcpy(&pbl, &Lu, 16);

    // ---- PV (full 64 d per wave) ----
    const u16* Vb = VtL[p];
    if (h == 0) {
#pragma unroll
      for (int dt = 0; dt < 4; ++dt) {
        const int d = dt * 16 + lq;
        const int dx = d & 7;
        const bf16x8 vh = *(const bf16x8*)(Vb + d * 64 + ((0 + lg) ^ dx) * 8);
        const bf16x8 vl = *(const bf16x8*)(Vb + d * 64 + ((4 + lg) ^ dx) * 8);
        Ya[dt] = MFMA(vh, pbl, Ya[dt]);
        Ya[dt] = MFMA(vl, pbh, Ya[dt]);
        Ya[dt] = MFMA(vh, pbh, Ya[dt]);
      }
    } else {
#pragma unroll
      for (int dt = 0; dt < 4; ++dt) {
        const int d = dt * 16 + lq;
        const int dx = d & 7;
        const bf16x8 v1h = *(const bf16x8*)(Vb + d * 64 + ((0 + lg) ^ dx) * 8);
        const bf16x8 v1l = *(const bf16x8*)(Vb + d * 64 + ((4 + lg) ^ dx) * 8);
        Yb[dt] = MFMA(v1h, pbl, Yb[dt]);
        Yb[dt] = MFMA(v1l, pbh, Yb[dt]);
        Yb[dt] = MFMA(v1h, pbh, Yb[dt]);
        const bf16x8 v2h = *(const bf16x8*)(Vb + (64 + d) * 64 + ((0 + lg) ^ dx) * 8);
        const bf16x8 v2l = *(const bf16x8*)(Vb + (64 + d) * 64 + ((4 + lg) ^ dx) * 8);
        Ya[dt] = MFMA(v2h, pbl, Ya[dt]);
        Ya[dt] = MFMA(v2l, pbh, Ya[dt]);
        Ya[dt] = MFMA(v2h, pbh, Ya[dt]);
      }
    }
  }

  // ---- epilogue: h1 publishes Y2 + l2 once; combine; split-bf16 out ----
  __syncthreads();
  float* y2x = (float*)VtL;  // [qs][lane][16] = 8 KB
  float* l2s = (float*)KsL;  // [qs*16 + lq]
  if (h == 1) {
    if (lane < 16) l2s[qs * 16 + lane] = l_run;
#pragma unroll
    for (int dt = 0; dt < 4; ++dt)
#pragma unroll
      for (int r = 0; r < 4; ++r)
        y2x[(qs * 64 + lane) * 16 + dt * 4 + r] = Yb[dt][r];
  }
  __syncthreads();
  if (h == 1) {
    const float inv2 = 1.0f / l_run;
#pragma unroll
    for (int dt = 0; dt < 4; ++dt) {
      u16 hh[4], ll[4];
#pragma unroll
      for (int r = 0; r < 4; ++r) split2(Ya[dt][r] * inv2, hh[r], ll[r]);
      u16* o = xo + qrow * 1024 + (hp + 4) * 64 + dt * 16 + lg * 4;
      *(uint2*)o = pack4(hh);
      *(uint2*)(o + 512) = pack4(ll);
    }
  } else {
    const float inv1 = 1.0f / l_run;
    const float inv2 = 1.0f / l2s[qs * 16 + lq];
    const float c1 = (1.0f + alpha) * inv1;
    const float c2 = alpha * lam_s * inv2;
#pragma unroll
    for (int dt = 0; dt < 4; ++dt) {
      u16 hh[4], ll[4];
#pragma unroll
      for (int r = 0; r < 4; ++r) {
        const float y2 = y2x[(qs * 64 + lane) * 16 + dt * 4 + r];
        split2(c1 * Ya[dt][r] - c2 * y2, hh[r], ll[r]);
      }
      u16* o = xo + qrow * 1024 + hp * 64 + dt * 16 + lg * 4;
      *(uint2*)o = pack4(hh);
      *(uint2*)(o + 512) = pack4(ll);
    }
  }
}

// =====================================================================
extern "C" void kernel_launch(void* const* d_in, const int* in_sizes, int n_in,
                              void* d_out, int out_size, void* d_ws, size_t ws_size,
                              hipStream_t stream) {
  const float* x_q   = (const float*)d_in[0];
  const float* x_kv  = (const float*)d_in[1];
  const int*   c_q   = (const int*)d_in[2];
  const int*   c_k   = (const int*)d_in[3];
  const float* alpha = (const float*)d_in[4];
  const float* Wq    = (const float*)d_in[5];
  const float* bq    = (const float*)d_in[6];
  const float* Wk    = (const float*)d_in[7];
  const float* bk    = (const float*)d_in[8];
  const float* Wv    = (const float*)d_in[9];
  const float* bv    = (const float*)d_in[10];
  const float* lq1   = (const float*)d_in[11];
  const float* lk1   = (const float*)d_in[12];
  const float* lq2   = (const float*)d_in[13];
  const float* lk2   = (const float*)d_in[14];
  const float* rpe   = (const float*)d_in[15];
  const float* Wp    = (const float*)d_in[16];
  const float* bp    = (const float*)d_in[17];

  // ws (28 MB): w2[0,4) | q2[4,12) | k2[12,20) | vbuf[20,28) (v2 then xa)
  // d_out (8 MB): vt during attention, then the final output.
  u16* w2   = (u16*)d_ws;
  u16* q2   = (u16*)((char*)d_ws + (4u << 20));
  u16* k2   = (u16*)((char*)d_ws + (12u << 20));
  u16* vbuf = (u16*)((char*)d_ws + (20u << 20));
  u16* vt   = (u16*)d_out;

  split_w4<<<dim3(256, 4), 256, 0, stream>>>(Wq, Wk, Wv, Wp, w2);
  gemm_qkv<<<dim3(8, 64, 3), 256, 0, stream>>>(x_q, x_kv, w2, bq, bk, bv,
                                               q2, k2, vbuf);
  vtbuild<<<dim3(16, 8, 4), 256, 0, stream>>>(vbuf, vt);
  attn_mfma<<<dim3(32, 4, NB), 256, 0, stream>>>(
      q2, k2, vt, c_q, c_k, alpha, lq1, lk1, lq2, lk2, rpe, vbuf);
  gemm_out<<<dim3(8, 64), 256, 0, stream>>>(vbuf, w2 + 3 * 524288, bp,
                                            (float*)d_out);
}

// Round 7
// 261.504 us; speedup vs baseline: 1.7757x; 1.1757x over previous
//
#include <hip/hip_runtime.h>
#include <cstddef>
#include <cstdint>

#define DIM   512
#define NSEQ  1024
#define NB    4

typedef unsigned short u16;
typedef short bf16x8 __attribute__((ext_vector_type(8)));
typedef float f32x4  __attribute__((ext_vector_type(4)));

#define MFMA(a, b, c) __builtin_amdgcn_mfma_f32_16x16x32_bf16(a, b, c, 0, 0, 0)

// RNE fp32 -> bf16 split: x ~= hi + lo (error ~2^-18 * |x|)
__device__ inline void split2(float x, u16& h, u16& l) {
  unsigned u = __float_as_uint(x);
  unsigned hb = (u + 0x7fffu + ((u >> 16) & 1u)) >> 16;
  float fh = __uint_as_float(hb << 16);
  float r = x - fh;
  unsigned v = __float_as_uint(r);
  unsigned lb = (v + 0x7fffu + ((v >> 16) & 1u)) >> 16;
  h = (u16)hb; l = (u16)lb;
}

__device__ inline uint2 pack4(const u16 a[4]) {
  return make_uint2((unsigned)a[0] | ((unsigned)a[1] << 16),
                    (unsigned)a[2] | ((unsigned)a[3] << 16));
}

__device__ inline uint4 pack8(const u16 a[8]) {
  return make_uint4((unsigned)a[0] | ((unsigned)a[1] << 16),
                    (unsigned)a[2] | ((unsigned)a[3] << 16),
                    (unsigned)a[4] | ((unsigned)a[5] << 16),
                    (unsigned)a[6] | ((unsigned)a[7] << 16));
}

__device__ inline u16 f2h(float x) {
  _Float16 h = (_Float16)x;
  u16 r; __builtin_memcpy(&r, &h, 2);
  return r;
}
__device__ inline float h2f(u16 b) {
  _Float16 h; __builtin_memcpy(&h, &b, 2);
  return (float)h;
}

// fp32 [rows][512] -> u16 [rows][1024] (hi plane | lo plane)
__global__ __launch_bounds__(256) void split_w4(
    const float* __restrict__ w0, const float* __restrict__ w1,
    const float* __restrict__ w2, const float* __restrict__ w3,
    u16* __restrict__ out) {
  const int y = blockIdx.y;
  const float* src = (y == 0) ? w0 : (y == 1) ? w1 : (y == 2) ? w2 : w3;
  u16* o0 = out + (size_t)y * 524288;
  const int e = (blockIdx.x * 256 + threadIdx.x) * 4;
  const int m = e >> 9, c = e & 511;
  const float4 v = *(const float4*)(src + e);
  u16 h[4], l[4];
  split2(v.x, h[0], l[0]); split2(v.y, h[1], l[1]);
  split2(v.z, h[2], l[2]); split2(v.w, h[3], l[3]);
  u16* o = o0 + (size_t)m * 1024 + c;
  *(uint2*)o = pack4(h);
  *(uint2*)(o + 512) = pack4(l);
}

#define GLDS(g, l)                                                        \
  __builtin_amdgcn_global_load_lds(                                       \
      (const __attribute__((address_space(1))) void*)(g),                 \
      (__attribute__((address_space(3))) void*)(l), 16, 0, 0)

// =====================================================================
// Dense RPE bias: biasT[b][head][k][q] fp16. One 32B gather per (q,k)
// serves all 8 heads (8x fewer L2 line-requests than in-attn gather).
// Block: 64q x 16k, 256 thr; LDS transpose for coalesced writes.
// =====================================================================
__global__ __launch_bounds__(256) void rpebuild(
    const int* __restrict__ cq, const int* __restrict__ ck,
    const float* __restrict__ rpe, u16* __restrict__ biasT) {
  __shared__ u16 Ts[8 * 16 * 64];  // [h][k][q] 16 KB
  const int t = threadIdx.x;
  const int q0 = blockIdx.x * 64, k0 = blockIdx.y * 16, b = blockIdx.z;
  const int qn = t & 63, kb = t >> 6;
  const int2 cqv = ((const int2*)cq)[b * NSEQ + q0 + qn];
#pragma unroll
  for (int j = 0; j < 4; ++j) {
    const int k = kb * 4 + j;
    const int2 ckv = ((const int2*)ck)[b * NSEQ + k0 + k];
    const int r0 = min(max(cqv.x - ckv.x + 128, 0), 256);
    const int r1 = min(max(cqv.y - ckv.y + 128, 0), 256);
    const float* rp = rpe + (size_t)(r0 * 257 + r1) * 8;
    const float4 f0 = *(const float4*)rp;
    const float4 f1 = *(const float4*)(rp + 4);
    u16* dst = Ts + k * 64 + qn;
    dst[0 * 1024] = f2h(f0.x); dst[1 * 1024] = f2h(f0.y);
    dst[2 * 1024] = f2h(f0.z); dst[3 * 1024] = f2h(f0.w);
    dst[4 * 1024] = f2h(f1.x); dst[5 * 1024] = f2h(f1.y);
    dst[6 * 1024] = f2h(f1.z); dst[7 * 1024] = f2h(f1.w);
  }
  __syncthreads();
#pragma unroll
  for (int i = 0; i < 4; ++i) {
    const int e = i * 256 + t;
    const int row = e >> 3, c8 = e & 7;  // row = h*16 + k
    const int hh = row >> 4, k = row & 15;
    const uint4 v = *(const uint4*)(Ts + row * 64 + c8 * 8);
    *(uint4*)(biasT + ((size_t)(b * 8 + hh) * 1024 + k0 + k) * 1024 +
              q0 + c8 * 8) = v;
  }
}

// =====================================================================
// Split-bf16 MFMA GEMM body (validated r2-r6).
// =====================================================================
template <int A_SPLIT, int OUT_SPLIT>
__device__ __forceinline__ void gemm_body(
    u16* __restrict__ Ah, u16* __restrict__ Al,
    u16* __restrict__ Bh, u16* __restrict__ Bl,
    const void* __restrict__ Ap, const u16* __restrict__ B2,
    const float* __restrict__ bias, void* __restrict__ outp,
    float scale, int m0, int n0) {
  const int tid = threadIdx.x;
  const int lane = tid & 63, w = tid >> 6;
  const int wm = (w & 1) * 32, wn = (w >> 1) * 32;

  const int sr  = w * 16 + (lane >> 3);
  const int scg = (lane & 7) ^ (sr & 7);
  const size_t bR = (size_t)(n0 + sr) * 1024 + scg * 8;
  const u16* gBh0 = B2 + bR;        const u16* gBh1 = B2 + bR + 8192;
  const u16* gBl0 = B2 + bR + 512;  const u16* gBl1 = B2 + bR + 8704;
  char* lBh = (char*)Bh + w * 2048; char* lBl = (char*)Bl + w * 2048;

  const u16* gAh0 = nullptr; const u16* gAh1 = nullptr;
  const u16* gAl0 = nullptr; const u16* gAl1 = nullptr;
  char* lAh = (char*)Ah + w * 2048; char* lAl = (char*)Al + w * 2048;
  const float* Af = nullptr;
  int arow = 0, apos0 = 0, apos1 = 0;
  if (A_SPLIT) {
    const size_t aR = (size_t)(m0 + sr) * 1024 + scg * 8;
    gAh0 = (const u16*)Ap + aR; gAh1 = gAh0 + 8192;
    gAl0 = gAh0 + 512;          gAl1 = gAh0 + 8704;
  } else {
    arow = tid >> 2;
    const int acg = tid & 3;
    Af = (const float*)Ap + (size_t)(m0 + arow) * 512 + acg * 8;
    apos0 = (acg ^ (arow & 7)) * 8;
    apos1 = ((acg + 4) ^ (arow & 7)) * 8;
  }

  const int fr = lane & 15, kq = lane >> 4, fx = lane & 7;
  int aoff[2][2], boff[2][2];
#pragma unroll
  for (int s = 0; s < 2; ++s)
#pragma unroll
    for (int t = 0; t < 2; ++t) {
      aoff[s][t] = (wm + t * 16 + fr) * 64 + (((s * 4 + kq) ^ fx)) * 8;
      boff[s][t] = (wn + t * 16 + fr) * 64 + (((s * 4 + kq) ^ fx)) * 8;
    }

  f32x4 acc[2][2] = {};
  for (int k0 = 0; k0 < 512; k0 += 64) {
    float4 f0, f1, f2, f3;
    if (!A_SPLIT) {
      f0 = *(const float4*)(Af + k0);
      f1 = *(const float4*)(Af + k0 + 4);
      f2 = *(const float4*)(Af + k0 + 32);
      f3 = *(const float4*)(Af + k0 + 36);
    }
    __syncthreads();
    GLDS(gBh0 + k0, lBh); GLDS(gBh1 + k0, lBh + 1024);
    GLDS(gBl0 + k0, lBl); GLDS(gBl1 + k0, lBl + 1024);
    if (A_SPLIT) {
      GLDS(gAh0 + k0, lAh); GLDS(gAh1 + k0, lAh + 1024);
      GLDS(gAl0 + k0, lAl); GLDS(gAl1 + k0, lAl + 1024);
    } else {
      u16 h8[8], l8[8];
      split2(f0.x, h8[0], l8[0]); split2(f0.y, h8[1], l8[1]);
      split2(f0.z, h8[2], l8[2]); split2(f0.w, h8[3], l8[3]);
      split2(f1.x, h8[4], l8[4]); split2(f1.y, h8[5], l8[5]);
      split2(f1.z, h8[6], l8[6]); split2(f1.w, h8[7], l8[7]);
      *(uint4*)(Ah + arow * 64 + apos0) = pack8(h8);
      *(uint4*)(Al + arow * 64 + apos0) = pack8(l8);
      split2(f2.x, h8[0], l8[0]); split2(f2.y, h8[1], l8[1]);
      split2(f2.z, h8[2], l8[2]); split2(f2.w, h8[3], l8[3]);
      split2(f3.x, h8[4], l8[4]); split2(f3.y, h8[5], l8[5]);
      split2(f3.z, h8[6], l8[6]); split2(f3.w, h8[7], l8[7]);
      *(uint4*)(Ah + arow * 64 + apos1) = pack8(h8);
      *(uint4*)(Al + arow * 64 + apos1) = pack8(l8);
    }
    __syncthreads();
#pragma unroll
    for (int s = 0; s < 2; ++s) {
      bf16x8 ah[2], al[2], bh[2], bl[2];
#pragma unroll
      for (int t = 0; t < 2; ++t) {
        ah[t] = *(const bf16x8*)(Ah + aoff[s][t]);
        al[t] = *(const bf16x8*)(Al + aoff[s][t]);
        bh[t] = *(const bf16x8*)(Bh + boff[s][t]);
        bl[t] = *(const bf16x8*)(Bl + boff[s][t]);
      }
#pragma unroll
      for (int i = 0; i < 2; ++i)
#pragma unroll
        for (int j = 0; j < 2; ++j) {
          acc[i][j] = MFMA(al[i], bh[j], acc[i][j]);
          acc[i][j] = MFMA(ah[i], bl[j], acc[i][j]);
          acc[i][j] = MFMA(ah[i], bh[j], acc[i][j]);
        }
    }
  }

  const int er = (lane >> 4) * 4, ec = lane & 15;
#pragma unroll
  for (int i = 0; i < 2; ++i)
#pragma unroll
    for (int j = 0; j < 2; ++j) {
      const int row = m0 + wm + i * 16 + er;
      const int col = n0 + wn + j * 16 + ec;
      const float bv = bias[col];
#pragma unroll
      for (int r = 0; r < 4; ++r) {
        const float v = (acc[i][j][r] + bv) * scale;
        if (OUT_SPLIT) {
          u16 hh, ll; split2(v, hh, ll);
          u16* o = (u16*)outp;
          o[(size_t)(row + r) * 1024 + col] = hh;
          o[(size_t)(row + r) * 1024 + 512 + col] = ll;
        } else {
          ((float*)outp)[(size_t)(row + r) * 512 + col] = v;
        }
      }
    }
}

__global__ __launch_bounds__(256) void gemm_qkv(
    const float* __restrict__ xq, const float* __restrict__ xkv,
    const u16* __restrict__ w2, const float* __restrict__ bq,
    const float* __restrict__ bk, const float* __restrict__ bv,
    u16* __restrict__ q2, u16* __restrict__ k2, u16* __restrict__ v2) {
  __shared__ __align__(16) u16 Ah[4096], Al[4096], Bh[4096], Bl[4096];
  const int z = blockIdx.z;
  const float* A = (z == 0) ? xq : xkv;
  const u16* B = w2 + (size_t)z * 524288;
  const float* bias = (z == 0) ? bq : (z == 1) ? bk : bv;
  u16* out = (z == 0) ? q2 : (z == 1) ? k2 : v2;
  const float scale = (z == 0) ? 0.125f : 1.0f;
  gemm_body<0, 1>(Ah, Al, Bh, Bl, A, B, bias, out, scale,
                  blockIdx.y * 64, blockIdx.x * 64);
}

__global__ __launch_bounds__(256) void gemm_out(
    const u16* __restrict__ xa2, const u16* __restrict__ w2p,
    const float* __restrict__ bp, float* __restrict__ out) {
  __shared__ __align__(16) u16 Ah[4096], Al[4096], Bh[4096], Bl[4096];
  gemm_body<1, 0>(Ah, Al, Bh, Bl, xa2, w2p, bp, out, 1.0f,
                  blockIdx.y * 64, blockIdx.x * 64);
}

// =====================================================================
// Transpose V (split planes) to vt[(b*512+d)][pl*1024 + k].
// =====================================================================
__global__ __launch_bounds__(256) void vtbuild(const u16* __restrict__ v2,
                                               u16* __restrict__ vt) {
  __shared__ u16 Ts[2][64][72];
  const int t = threadIdx.x;
  const int b = blockIdx.z, d0 = blockIdx.y * 64, k0 = blockIdx.x * 64;
  const int r = t >> 3, c8 = (t & 7) * 8;
#pragma unroll
  for (int half = 0; half < 2; ++half) {
    const int kk = r + half * 32;
    const size_t row = (size_t)(b * 1024 + k0 + kk) * 1024;
#pragma unroll
    for (int pl = 0; pl < 2; ++pl)
      *(uint4*)&Ts[pl][kk][c8] = *(const uint4*)(v2 + row + pl * 512 + d0 + c8);
  }
  __syncthreads();
#pragma unroll
  for (int half = 0; half < 2; ++half) {
    const int dd = r + half * 32;
#pragma unroll
    for (int pl = 0; pl < 2; ++pl) {
      u16 tmp[8];
#pragma unroll
      for (int i = 0; i < 8; ++i) tmp[i] = Ts[pl][c8 + i][dd];
      *(uint4*)(vt + (size_t)(b * 512 + d0 + dd) * 2048 + pl * 1024 + k0 + c8) =
          *(uint4*)tmp;
    }
  }
}

// =====================================================================
// MFMA differential flash attention, v3.1.
// DENSE=1: bias from dense fp16 biasT[b][head][k][q] (coalesced loads).
// DENSE=0: r6 fallback (in-kernel rpe gather pipeline).
// Structure otherwise identical to r6 (single barrier per K-iter,
// register-P via shuffles, h1 owns Y2/Y3).
// =====================================================================
template <int DENSE>
__global__ __launch_bounds__(256) void attn_mfma(
    const u16* __restrict__ q2, const u16* __restrict__ k2,
    const u16* __restrict__ vtg, const int* __restrict__ cq,
    const int* __restrict__ ck, const float* __restrict__ amap,
    const float* __restrict__ lq1, const float* __restrict__ lk1,
    const float* __restrict__ lq2, const float* __restrict__ lk2,
    const float* __restrict__ rpe, const u16* __restrict__ biasT,
    u16* __restrict__ xo) {
  __shared__ __align__(16) u16 KsL[2][8192];
  __shared__ __align__(16) u16 VtL[2][8192];
  __shared__ float lam_s;

  const int tid = threadIdx.x;
  const int lane = tid & 63, w = tid >> 6;
  const int h = w >> 1, qs = w & 1;
  const int hp = blockIdx.y, b = blockIdx.z;
  const int q0 = blockIdx.x * 32;
  const int head = hp + 4 * h;
  const int lq = lane & 15, lg = lane >> 4;
  const int q = qs * 16 + lq;
  const size_t qrow = (size_t)(b * NSEQ + q0 + q);

  if (tid < 64) {
    float p1 = lq1[hp * 64 + tid] * lk1[hp * 64 + tid];
    float p2 = lq2[hp * 64 + tid] * lk2[hp * 64 + tid];
#pragma unroll
    for (int m = 32; m >= 1; m >>= 1) {
      p1 += __shfl_xor(p1, m, 64);
      p2 += __shfl_xor(p2, m, 64);
    }
    if (tid == 0) lam_s = __expf(p1) - __expf(p2) + 0.8f;
  }

  const float alpha = amap[qrow];
  int cq0 = 0, cq1 = 0;
  if (!DENSE) {
    cq0 = cq[qrow * 2 + 0];
    cq1 = cq[qrow * 2 + 1];
  }

  // Q B-frags in registers (q2 pre-scaled by 1/8)
  bf16x8 Qf[2][2];
#pragma unroll
  for (int ks = 0; ks < 2; ++ks)
#pragma unroll
    for (int pl = 0; pl < 2; ++pl)
      Qf[ks][pl] = *(const bf16x8*)(q2 + qrow * 1024 + pl * 512 + head * 64 +
                                    ks * 32 + lg * 8);

  f32x4 Ya[4] = {};  // h0: Y1 ; h1: Y3
  f32x4 Yb[4] = {};  // h1: Y2
  float m_run = -1e30f, l_run = 0.0f;

  const int sgrp = lane >> 3, scc = (lane & 7) ^ sgrp;
  const int cw = w * 4;

  auto stage = [&](int it, int p) {
#pragma unroll
    for (int i = 0; i < 4; ++i) {
      const int c = cw + i;
      const int sh = c >> 3, spl = (c >> 2) & 1, sub = c & 3;
      const int r = sub * 8 + sgrp;
      const u16* src = k2 + (size_t)(b * NSEQ + it * 32 + r) * 1024 + spl * 512 +
                       (hp + 4 * sh) * 64 + scc * 8;
      GLDS(src, (char*)KsL[p] + c * 1024);
    }
#pragma unroll
    for (int i = 0; i < 4; ++i) {
      const int c = cw + i;
      const int sh = c >> 3, dg = c & 7;
      const int d = dg * 8 + sgrp;
      const int spl = scc >> 2, kc = scc & 3;
      const u16* src = vtg + (size_t)(b * 512 + (hp + 4 * sh) * 64 + d) * 2048 +
                       spl * 1024 + it * 32 + kc * 8;
      GLDS(src, (char*)VtL[p] + c * 1024);
    }
  };

  // DENSE: coalesced fp16 bias loads; base row for this (b, head, q-lane)
  const u16* bT = DENSE
      ? biasT + ((size_t)(b * 8 + head) * 1024) * 1024 + q0 + qs * 16 + lq
      : nullptr;

  // Fallback (r6): register RPE pipeline
  const int2* ck2 = (const int2*)ck;
  int2 ncA[8], ncB[8];
  float rv[8];
  auto loadNC = [&](int it, int2* nc) {
    const int base = b * NSEQ + it * 32 + lg * 4;
#pragma unroll
    for (int kt = 0; kt < 2; ++kt)
#pragma unroll
      for (int r = 0; r < 4; ++r) nc[kt * 4 + r] = ck2[base + kt * 16 + r];
  };
  auto loadRPE = [&](const int2* nc, float* dst) {
#pragma unroll
    for (int e = 0; e < 8; ++e) {
      const int r0 = min(max(cq0 - nc[e].x + 128, 0), 256);
      const int r1 = min(max(cq1 - nc[e].y + 128, 0), 256);
      dst[e] = rpe[(r0 * 257 + r1) * 8 + head];
    }
  };

  stage(0, 0);
  if (!DENSE) {
    loadNC(0, ncA);
    loadRPE(ncA, rv);
    loadNC(1, ncB);
  }

  for (int it = 0; it < 32; ++it) {
    const int p = it & 1;
    __syncthreads();  // drains staging of tile it (in flight a full iter)
    if (it + 1 < 32) stage(it + 1, p ^ 1);

    // DENSE: issue current tile's bias loads now (consumed after S MFMA)
    u16 rb[8];
    if (DENSE) {
      const u16* bt = bT + (size_t)(it * 32) * 1024;
#pragma unroll
      for (int kt = 0; kt < 2; ++kt)
#pragma unroll
        for (int r = 0; r < 4; ++r)
          rb[kt * 4 + r] = bt[(size_t)(kt * 16 + lg * 4 + r) * 1024];
    }

    // ---- S^T = K . Q^T (3-term split) ----
    const u16* Kb = KsL[p];
    f32x4 st[2] = {};
#pragma unroll
    for (int kt = 0; kt < 2; ++kt) {
      const int krow = kt * 16 + lq;
      const int rx = krow & 7;
#pragma unroll
      for (int ks = 0; ks < 2; ++ks) {
        const int phys = (ks * 4 + lg) ^ rx;
        const bf16x8 khi = *(const bf16x8*)(Kb + ((h * 2 + 0) * 32 + krow) * 64 + phys * 8);
        const bf16x8 klo = *(const bf16x8*)(Kb + ((h * 2 + 1) * 32 + krow) * 64 + phys * 8);
        st[kt] = MFMA(khi, Qf[ks][1], st[kt]);
        st[kt] = MFMA(klo, Qf[ks][0], st[kt]);
        st[kt] = MFMA(khi, Qf[ks][0], st[kt]);
      }
    }

    // ---- online softmax (q = lane col, k = regs) ----
    float sv[2][4];
    float mx = -1e30f;
#pragma unroll
    for (int kt = 0; kt < 2; ++kt)
#pragma unroll
      for (int r = 0; r < 4; ++r) {
        const float bias = DENSE ? h2f(rb[kt * 4 + r]) : rv[kt * 4 + r];
        const float s = st[kt][r] + bias;
        sv[kt][r] = s;
        mx = fmaxf(mx, s);
      }
    mx = fmaxf(mx, __shfl_xor(mx, 16, 64));
    mx = fmaxf(mx, __shfl_xor(mx, 32, 64));
    const float mnew = fmaxf(m_run, mx);
    const float a = __expf(m_run - mnew);
    m_run = mnew;
    float pr[2][4], ps = 0.0f;
#pragma unroll
    for (int kt = 0; kt < 2; ++kt)
#pragma unroll
      for (int r = 0; r < 4; ++r) {
        pr[kt][r] = __expf(sv[kt][r] - mnew);
        ps += pr[kt][r];
      }
    ps += __shfl_xor(ps, 16, 64);
    ps += __shfl_xor(ps, 32, 64);
    l_run = l_run * a + ps;
#pragma unroll
    for (int dt = 0; dt < 4; ++dt) Ya[dt] *= a;
    if (h == 1) {
#pragma unroll
      for (int dt = 0; dt < 4; ++dt) Yb[dt] *= a;
    }

    if (!DENSE) {
      const int itn = (it + 2 > 31) ? 31 : it + 2;
      if ((it & 1) == 0) { loadRPE(ncB, rv); loadNC(itn, ncA); }
      else               { loadRPE(ncA, rv); loadNC(itn, ncB); }
    }

    // ---- P: D-layout -> B-operand frag via shuffles, split-bf16 ----
    const int srcA = lq + ((lg & 1) << 5);
    float pj[8];
#pragma unroll
    for (int r = 0; r < 4; ++r) {
      const float t0 = __shfl(pr[0][r], srcA);
      const float t1 = __shfl(pr[1][r], srcA);
      pj[r] = (lg >= 2) ? t1 : t0;
      const float u0 = __shfl(pr[0][r], srcA + 16);
      const float u1 = __shfl(pr[1][r], srcA + 16);
      pj[4 + r] = (lg >= 2) ? u1 : u0;
    }
    u16 phh[8], pll[8];
#pragma unroll
    for (int e = 0; e < 8; ++e) split2(pj[e], phh[e], pll[e]);
    const uint4 Hu = pack8(phh), Lu = pack8(pll);
    bf16x8 pbh, pbl;
    __builtin_memcpy(&pbh, &Hu, 16);
    __builtin_memcpy(&pbl, &Lu, 16);

    // ---- PV (full 64 d per wave) ----
    const u16* Vb = VtL[p];
    if (h == 0) {
#pragma unroll
      for (int dt = 0; dt < 4; ++dt) {
        const int d = dt * 16 + lq;
        const int dx = d & 7;
        const bf16x8 vh = *(const bf16x8*)(Vb + d * 64 + ((0 + lg) ^ dx) * 8);
        const bf16x8 vl = *(const bf16x8*)(Vb + d * 64 + ((4 + lg) ^ dx) * 8);
        Ya[dt] = MFMA(vh, pbl, Ya[dt]);
        Ya[dt] = MFMA(vl, pbh, Ya[dt]);
        Ya[dt] = MFMA(vh, pbh, Ya[dt]);
      }
    } else {
#pragma unroll
      for (int dt = 0; dt < 4; ++dt) {
        const int d = dt * 16 + lq;
        const int dx = d & 7;
        const bf16x8 v1h = *(const bf16x8*)(Vb + d * 64 + ((0 + lg) ^ dx) * 8);
        const bf16x8 v1l = *(const bf16x8*)(Vb + d * 64 + ((4 + lg) ^ dx) * 8);
        Yb[dt] = MFMA(v1h, pbl, Yb[dt]);
        Yb[dt] = MFMA(v1l, pbh, Yb[dt]);
        Yb[dt] = MFMA(v1h, pbh, Yb[dt]);
        const bf16x8 v2h = *(const bf16x8*)(Vb + (64 + d) * 64 + ((0 + lg) ^ dx) * 8);
        const bf16x8 v2l = *(const bf16x8*)(Vb + (64 + d) * 64 + ((4 + lg) ^ dx) * 8);
        Ya[dt] = MFMA(v2h, pbl, Ya[dt]);
        Ya[dt] = MFMA(v2l, pbh, Ya[dt]);
        Ya[dt] = MFMA(v2h, pbh, Ya[dt]);
      }
    }
  }

  // ---- epilogue: h1 publishes Y2 + l2 once; combine; split-bf16 out ----
  __syncthreads();
  float* y2x = (float*)VtL;  // [qs][lane][16] = 8 KB
  float* l2s = (float*)KsL;  // [qs*16 + lq]
  if (h == 1) {
    if (lane < 16) l2s[qs * 16 + lane] = l_run;
#pragma unroll
    for (int dt = 0; dt < 4; ++dt)
#pragma unroll
      for (int r = 0; r < 4; ++r)
        y2x[(qs * 64 + lane) * 16 + dt * 4 + r] = Yb[dt][r];
  }
  __syncthreads();
  if (h == 1) {
    const float inv2 = 1.0f / l_run;
#pragma unroll
    for (int dt = 0; dt < 4; ++dt) {
      u16 hh[4], ll[4];
#pragma unroll
      for (int r = 0; r < 4; ++r) split2(Ya[dt][r] * inv2, hh[r], ll[r]);
      u16* o = xo + qrow * 1024 + (hp + 4) * 64 + dt * 16 + lg * 4;
      *(uint2*)o = pack4(hh);
      *(uint2*)(o + 512) = pack4(ll);
    }
  } else {
    const float inv1 = 1.0f / l_run;
    const float inv2 = 1.0f / l2s[qs * 16 + lq];
    const float c1 = (1.0f + alpha) * inv1;
    const float c2 = alpha * lam_s * inv2;
#pragma unroll
    for (int dt = 0; dt < 4; ++dt) {
      u16 hh[4], ll[4];
#pragma unroll
      for (int r = 0; r < 4; ++r) {
        const float y2 = y2x[(qs * 64 + lane) * 16 + dt * 4 + r];
        split2(c1 * Ya[dt][r] - c2 * y2, hh[r], ll[r]);
      }
      u16* o = xo + qrow * 1024 + hp * 64 + dt * 16 + lg * 4;
      *(uint2*)o = pack4(hh);
      *(uint2*)(o + 512) = pack4(ll);
    }
  }
}

// =====================================================================
extern "C" void kernel_launch(void* const* d_in, const int* in_sizes, int n_in,
                              void* d_out, int out_size, void* d_ws, size_t ws_size,
                              hipStream_t stream) {
  const float* x_q   = (const float*)d_in[0];
  const float* x_kv  = (const float*)d_in[1];
  const int*   c_q   = (const int*)d_in[2];
  const int*   c_k   = (const int*)d_in[3];
  const float* alpha = (const float*)d_in[4];
  const float* Wq    = (const float*)d_in[5];
  const float* bq    = (const float*)d_in[6];
  const float* Wk    = (const float*)d_in[7];
  const float* bk    = (const float*)d_in[8];
  const float* Wv    = (const float*)d_in[9];
  const float* bv    = (const float*)d_in[10];
  const float* lq1   = (const float*)d_in[11];
  const float* lk1   = (const float*)d_in[12];
  const float* lq2   = (const float*)d_in[13];
  const float* lk2   = (const float*)d_in[14];
  const float* rpe   = (const float*)d_in[15];
  const float* Wp    = (const float*)d_in[16];
  const float* bp    = (const float*)d_in[17];

  // ws: w2[0,4) | q2[4,12) | k2[12,20) | vbuf[20,28) (v2 then xa)
  //     | biasT[28,92) if ws_size permits.  d_out: vt then final output.
  u16* w2    = (u16*)d_ws;
  u16* q2    = (u16*)((char*)d_ws + (4u << 20));
  u16* k2    = (u16*)((char*)d_ws + (12u << 20));
  u16* vbuf  = (u16*)((char*)d_ws + (20u << 20));
  u16* biasT = (u16*)((char*)d_ws + (28u << 20));
  u16* vt    = (u16*)d_out;
  const bool dense = ws_size >= ((size_t)92 << 20);

  split_w4<<<dim3(256, 4), 256, 0, stream>>>(Wq, Wk, Wv, Wp, w2);
  if (dense)
    rpebuild<<<dim3(16, 64, 4), 256, 0, stream>>>(c_q, c_k, rpe, biasT);
  gemm_qkv<<<dim3(8, 64, 3), 256, 0, stream>>>(x_q, x_kv, w2, bq, bk, bv,
                                               q2, k2, vbuf);
  vtbuild<<<dim3(16, 8, 4), 256, 0, stream>>>(vbuf, vt);
  if (dense)
    attn_mfma<1><<<dim3(32, 4, NB), 256, 0, stream>>>(
        q2, k2, vt, c_q, c_k, alpha, lq1, lk1, lq2, lk2, rpe, biasT, vbuf);
  else
    attn_mfma<0><<<dim3(32, 4, NB), 256, 0, stream>>>(
        q2, k2, vt, c_q, c_k, alpha, lq1, lk1, lq2, lk2, rpe, biasT, vbuf);
  gemm_out<<<dim3(8, 64), 256, 0, stream>>>(vbuf, w2 + 3 * 524288, bp,
                                            (float*)d_out);
}

// Round 8
// 259.535 us; speedup vs baseline: 1.7892x; 1.0076x over previous
//
#include <hip/hip_runtime.h>
#include <cstddef>
#include <cstdint>

#define DIM   512
#define NSEQ  1024
#define NB    4

typedef unsigned short u16;
typedef short bf16x8 __attribute__((ext_vector_type(8)));
typedef float f32x4  __attribute__((ext_vector_type(4)));

#define MFMA(a, b, c) __builtin_amdgcn_mfma_f32_16x16x32_bf16(a, b, c, 0, 0, 0)

// RNE fp32 -> bf16 split: x ~= hi + lo (error ~2^-18 * |x|)
__device__ inline void split2(float x, u16& h, u16& l) {
  unsigned u = __float_as_uint(x);
  unsigned hb = (u + 0x7fffu + ((u >> 16) & 1u)) >> 16;
  float fh = __uint_as_float(hb << 16);
  float r = x - fh;
  unsigned v = __float_as_uint(r);
  unsigned lb = (v + 0x7fffu + ((v >> 16) & 1u)) >> 16;
  h = (u16)hb; l = (u16)lb;
}

__device__ inline uint2 pack4(const u16 a[4]) {
  return make_uint2((unsigned)a[0] | ((unsigned)a[1] << 16),
                    (unsigned)a[2] | ((unsigned)a[3] << 16));
}

__device__ inline uint4 pack8(const u16 a[8]) {
  return make_uint4((unsigned)a[0] | ((unsigned)a[1] << 16),
                    (unsigned)a[2] | ((unsigned)a[3] << 16),
                    (unsigned)a[4] | ((unsigned)a[5] << 16),
                    (unsigned)a[6] | ((unsigned)a[7] << 16));
}

__device__ inline u16 f2h(float x) {
  _Float16 h = (_Float16)x;
  u16 r; __builtin_memcpy(&r, &h, 2);
  return r;
}
__device__ inline float h2f(u16 b) {
  _Float16 h; __builtin_memcpy(&h, &b, 2);
  return (float)h;
}

// fp32 [rows][512] -> u16 [rows][1024] (hi plane | lo plane)
__global__ __launch_bounds__(256) void split_w4(
    const float* __restrict__ w0, const float* __restrict__ w1,
    const float* __restrict__ w2, const float* __restrict__ w3,
    u16* __restrict__ out) {
  const int y = blockIdx.y;
  const float* src = (y == 0) ? w0 : (y == 1) ? w1 : (y == 2) ? w2 : w3;
  u16* o0 = out + (size_t)y * 524288;
  const int e = (blockIdx.x * 256 + threadIdx.x) * 4;
  const int m = e >> 9, c = e & 511;
  const float4 v = *(const float4*)(src + e);
  u16 h[4], l[4];
  split2(v.x, h[0], l[0]); split2(v.y, h[1], l[1]);
  split2(v.z, h[2], l[2]); split2(v.w, h[3], l[3]);
  u16* o = o0 + (size_t)m * 1024 + c;
  *(uint2*)o = pack4(h);
  *(uint2*)(o + 512) = pack4(l);
}

#define GLDS(g, l)                                                        \
  __builtin_amdgcn_global_load_lds(                                       \
      (const __attribute__((address_space(1))) void*)(g),                 \
      (__attribute__((address_space(3))) void*)(l), 16, 0, 0)

// =====================================================================
// Dense RPE bias: biasT[b][head][k][q] fp16. One 32B gather per (q,k)
// serves all 8 heads. (validated r7: attn 174 -> 94 us)
// =====================================================================
__global__ __launch_bounds__(256) void rpebuild(
    const int* __restrict__ cq, const int* __restrict__ ck,
    const float* __restrict__ rpe, u16* __restrict__ biasT) {
  __shared__ u16 Ts[8 * 16 * 64];  // [h][k][q] 16 KB
  const int t = threadIdx.x;
  const int q0 = blockIdx.x * 64, k0 = blockIdx.y * 16, b = blockIdx.z;
  const int qn = t & 63, kb = t >> 6;
  const int2 cqv = ((const int2*)cq)[b * NSEQ + q0 + qn];
#pragma unroll
  for (int j = 0; j < 4; ++j) {
    const int k = kb * 4 + j;
    const int2 ckv = ((const int2*)ck)[b * NSEQ + k0 + k];
    const int r0 = min(max(cqv.x - ckv.x + 128, 0), 256);
    const int r1 = min(max(cqv.y - ckv.y + 128, 0), 256);
    const float* rp = rpe + (size_t)(r0 * 257 + r1) * 8;
    const float4 f0 = *(const float4*)rp;
    const float4 f1 = *(const float4*)(rp + 4);
    u16* dst = Ts + k * 64 + qn;
    dst[0 * 1024] = f2h(f0.x); dst[1 * 1024] = f2h(f0.y);
    dst[2 * 1024] = f2h(f0.z); dst[3 * 1024] = f2h(f0.w);
    dst[4 * 1024] = f2h(f1.x); dst[5 * 1024] = f2h(f1.y);
    dst[6 * 1024] = f2h(f1.z); dst[7 * 1024] = f2h(f1.w);
  }
  __syncthreads();
#pragma unroll
  for (int i = 0; i < 4; ++i) {
    const int e = i * 256 + t;
    const int row = e >> 3, c8 = e & 7;  // row = h*16 + k
    const int hh = row >> 4, k = row & 15;
    const uint4 v = *(const uint4*)(Ts + row * 64 + c8 * 8);
    *(uint4*)(biasT + ((size_t)(b * 8 + hh) * 1024 + k0 + k) * 1024 +
              q0 + c8 * 8) = v;
  }
}

// =====================================================================
// Split-bf16 MFMA GEMM body (validated r2-r7).
// OUT_MODE: 0 = fp32 [m][512]; 1 = split u16 [m][1024];
//           2 = vt layout [(b*512+col)][2048] (hi k | lo k) — V GEMM.
// =====================================================================
template <int A_SPLIT, int OUT_MODE>
__device__ __forceinline__ void gemm_body(
    u16* __restrict__ Ah, u16* __restrict__ Al,
    u16* __restrict__ Bh, u16* __restrict__ Bl,
    const void* __restrict__ Ap, const u16* __restrict__ B2,
    const float* __restrict__ bias, void* __restrict__ outp,
    float scale, int m0, int n0) {
  const int tid = threadIdx.x;
  const int lane = tid & 63, w = tid >> 6;
  const int wm = (w & 1) * 32, wn = (w >> 1) * 32;

  const int sr  = w * 16 + (lane >> 3);
  const int scg = (lane & 7) ^ (sr & 7);
  const size_t bR = (size_t)(n0 + sr) * 1024 + scg * 8;
  const u16* gBh0 = B2 + bR;        const u16* gBh1 = B2 + bR + 8192;
  const u16* gBl0 = B2 + bR + 512;  const u16* gBl1 = B2 + bR + 8704;
  char* lBh = (char*)Bh + w * 2048; char* lBl = (char*)Bl + w * 2048;

  const u16* gAh0 = nullptr; const u16* gAh1 = nullptr;
  const u16* gAl0 = nullptr; const u16* gAl1 = nullptr;
  char* lAh = (char*)Ah + w * 2048; char* lAl = (char*)Al + w * 2048;
  const float* Af = nullptr;
  int arow = 0, apos0 = 0, apos1 = 0;
  if (A_SPLIT) {
    const size_t aR = (size_t)(m0 + sr) * 1024 + scg * 8;
    gAh0 = (const u16*)Ap + aR; gAh1 = gAh0 + 8192;
    gAl0 = gAh0 + 512;          gAl1 = gAh0 + 8704;
  } else {
    arow = tid >> 2;
    const int acg = tid & 3;
    Af = (const float*)Ap + (size_t)(m0 + arow) * 512 + acg * 8;
    apos0 = (acg ^ (arow & 7)) * 8;
    apos1 = ((acg + 4) ^ (arow & 7)) * 8;
  }

  const int fr = lane & 15, kq = lane >> 4, fx = lane & 7;
  int aoff[2][2], boff[2][2];
#pragma unroll
  for (int s = 0; s < 2; ++s)
#pragma unroll
    for (int t = 0; t < 2; ++t) {
      aoff[s][t] = (wm + t * 16 + fr) * 64 + (((s * 4 + kq) ^ fx)) * 8;
      boff[s][t] = (wn + t * 16 + fr) * 64 + (((s * 4 + kq) ^ fx)) * 8;
    }

  f32x4 acc[2][2] = {};
  for (int k0 = 0; k0 < 512; k0 += 64) {
    float4 f0, f1, f2, f3;
    if (!A_SPLIT) {
      f0 = *(const float4*)(Af + k0);
      f1 = *(const float4*)(Af + k0 + 4);
      f2 = *(const float4*)(Af + k0 + 32);
      f3 = *(const float4*)(Af + k0 + 36);
    }
    __syncthreads();
    GLDS(gBh0 + k0, lBh); GLDS(gBh1 + k0, lBh + 1024);
    GLDS(gBl0 + k0, lBl); GLDS(gBl1 + k0, lBl + 1024);
    if (A_SPLIT) {
      GLDS(gAh0 + k0, lAh); GLDS(gAh1 + k0, lAh + 1024);
      GLDS(gAl0 + k0, lAl); GLDS(gAl1 + k0, lAl + 1024);
    } else {
      u16 h8[8], l8[8];
      split2(f0.x, h8[0], l8[0]); split2(f0.y, h8[1], l8[1]);
      split2(f0.z, h8[2], l8[2]); split2(f0.w, h8[3], l8[3]);
      split2(f1.x, h8[4], l8[4]); split2(f1.y, h8[5], l8[5]);
      split2(f1.z, h8[6], l8[6]); split2(f1.w, h8[7], l8[7]);
      *(uint4*)(Ah + arow * 64 + apos0) = pack8(h8);
      *(uint4*)(Al + arow * 64 + apos0) = pack8(l8);
      split2(f2.x, h8[0], l8[0]); split2(f2.y, h8[1], l8[1]);
      split2(f2.z, h8[2], l8[2]); split2(f2.w, h8[3], l8[3]);
      split2(f3.x, h8[4], l8[4]); split2(f3.y, h8[5], l8[5]);
      split2(f3.z, h8[6], l8[6]); split2(f3.w, h8[7], l8[7]);
      *(uint4*)(Ah + arow * 64 + apos1) = pack8(h8);
      *(uint4*)(Al + arow * 64 + apos1) = pack8(l8);
    }
    __syncthreads();
#pragma unroll
    for (int s = 0; s < 2; ++s) {
      bf16x8 ah[2], al[2], bh[2], bl[2];
#pragma unroll
      for (int t = 0; t < 2; ++t) {
        ah[t] = *(const bf16x8*)(Ah + aoff[s][t]);
        al[t] = *(const bf16x8*)(Al + aoff[s][t]);
        bh[t] = *(const bf16x8*)(Bh + boff[s][t]);
        bl[t] = *(const bf16x8*)(Bl + boff[s][t]);
      }
#pragma unroll
      for (int i = 0; i < 2; ++i)
#pragma unroll
        for (int j = 0; j < 2; ++j) {
          acc[i][j] = MFMA(al[i], bh[j], acc[i][j]);
          acc[i][j] = MFMA(ah[i], bl[j], acc[i][j]);
          acc[i][j] = MFMA(ah[i], bh[j], acc[i][j]);
        }
    }
  }

  const int er = (lane >> 4) * 4, ec = lane & 15;
#pragma unroll
  for (int i = 0; i < 2; ++i)
#pragma unroll
    for (int j = 0; j < 2; ++j) {
      const int row = m0 + wm + i * 16 + er;
      const int col = n0 + wn + j * 16 + ec;
      const float bv = bias[col];
      if (OUT_MODE == 2) {
        u16 hh[4], ll[4];
#pragma unroll
        for (int r = 0; r < 4; ++r)
          split2((acc[i][j][r] + bv) * scale, hh[r], ll[r]);
        const int bb = row >> 10, kk = row & 1023;
        u16* o = (u16*)outp + ((size_t)(bb * 512 + col)) * 2048 + kk;
        *(uint2*)o = pack4(hh);
        *(uint2*)(o + 1024) = pack4(ll);
      } else {
#pragma unroll
        for (int r = 0; r < 4; ++r) {
          const float v = (acc[i][j][r] + bv) * scale;
          if (OUT_MODE == 1) {
            u16 hh, ll; split2(v, hh, ll);
            u16* o = (u16*)outp;
            o[(size_t)(row + r) * 1024 + col] = hh;
            o[(size_t)(row + r) * 1024 + 512 + col] = ll;
          } else {
            ((float*)outp)[(size_t)(row + r) * 512 + col] = v;
          }
        }
      }
    }
}

// Fused Q/K/V projections; z==2 (V) writes vt layout directly.
__global__ __launch_bounds__(256) void gemm_qkv(
    const float* __restrict__ xq, const float* __restrict__ xkv,
    const u16* __restrict__ w2, const float* __restrict__ bq,
    const float* __restrict__ bk, const float* __restrict__ bv,
    u16* __restrict__ q2, u16* __restrict__ k2, u16* __restrict__ vt) {
  __shared__ __align__(16) u16 Ah[4096], Al[4096], Bh[4096], Bl[4096];
  const int z = blockIdx.z;
  const float* A = (z == 0) ? xq : xkv;
  const u16* B = w2 + (size_t)z * 524288;
  const int m0 = blockIdx.y * 64, n0 = blockIdx.x * 64;
  if (z == 2) {
    gemm_body<0, 2>(Ah, Al, Bh, Bl, A, B, bv, vt, 1.0f, m0, n0);
  } else if (z == 1) {
    gemm_body<0, 1>(Ah, Al, Bh, Bl, A, B, bk, k2, 1.0f, m0, n0);
  } else {
    gemm_body<0, 1>(Ah, Al, Bh, Bl, A, B, bq, q2, 0.125f, m0, n0);
  }
}

__global__ __launch_bounds__(256) void gemm_out(
    const u16* __restrict__ xa2, const u16* __restrict__ w2p,
    const float* __restrict__ bp, float* __restrict__ out) {
  __shared__ __align__(16) u16 Ah[4096], Al[4096], Bh[4096], Bl[4096];
  gemm_body<1, 0>(Ah, Al, Bh, Bl, xa2, w2p, bp, out, 1.0f,
                  blockIdx.y * 64, blockIdx.x * 64);
}

// =====================================================================
// MFMA differential flash attention, v4: 512-thread blocks (64 q),
// 8 waves = (h, qs 0..3) -> 2 blocks/CU x 8 waves = 4 waves/SIMD
// (vs 2 in r7). Same single barrier/K-iter, register-P shuffles,
// dense fp16 bias loads, h1 owns Y2/Y3. LDS 64.5 KB.
// =====================================================================
__global__ __launch_bounds__(512) void attn_mfma(
    const u16* __restrict__ q2, const u16* __restrict__ k2,
    const u16* __restrict__ vtg, const float* __restrict__ amap,
    const float* __restrict__ lq1, const float* __restrict__ lk1,
    const float* __restrict__ lq2, const float* __restrict__ lk2,
    const u16* __restrict__ biasT, u16* __restrict__ xo) {
  __shared__ __align__(16) u16 KsL[2][8192];  // [buf][(h*2+pl)*32+k][64 d]
  __shared__ __align__(16) u16 VtL[2][8192];  // [buf][h*64+d][hi32k|lo32k]
  __shared__ float lam_s;

  const int tid = threadIdx.x;
  const int lane = tid & 63, w = tid >> 6;
  const int h = w >> 2, qs = w & 3;
  const int hp = blockIdx.y, b = blockIdx.z;
  const int q0 = blockIdx.x * 64;
  const int head = hp + 4 * h;
  const int lq = lane & 15, lg = lane >> 4;
  const int q = qs * 16 + lq;
  const size_t qrow = (size_t)(b * NSEQ + q0 + q);

  if (tid < 64) {
    float p1 = lq1[hp * 64 + tid] * lk1[hp * 64 + tid];
    float p2 = lq2[hp * 64 + tid] * lk2[hp * 64 + tid];
#pragma unroll
    for (int m = 32; m >= 1; m >>= 1) {
      p1 += __shfl_xor(p1, m, 64);
      p2 += __shfl_xor(p2, m, 64);
    }
    if (tid == 0) lam_s = __expf(p1) - __expf(p2) + 0.8f;
  }

  const float alpha = amap[qrow];

  // Q B-frags in registers (q2 pre-scaled by 1/8)
  bf16x8 Qf[2][2];
#pragma unroll
  for (int ks = 0; ks < 2; ++ks)
#pragma unroll
    for (int pl = 0; pl < 2; ++pl)
      Qf[ks][pl] = *(const bf16x8*)(q2 + qrow * 1024 + pl * 512 + head * 64 +
                                    ks * 32 + lg * 8);

  f32x4 Ya[4] = {};  // h0: Y1 ; h1: Y3
  f32x4 Yb[4] = {};  // h1: Y2
  float m_run = -1e30f, l_run = 0.0f;

  const int sgrp = lane >> 3, scc = (lane & 7) ^ sgrp;
  const int cw = w * 2;  // 8 waves x 2 chunks = 16 chunks each for K and Vt

  auto stage = [&](int it, int p) {
#pragma unroll
    for (int i = 0; i < 2; ++i) {
      const int c = cw + i;
      const int sh = c >> 3, spl = (c >> 2) & 1, sub = c & 3;
      const int r = sub * 8 + sgrp;
      const u16* src = k2 + (size_t)(b * NSEQ + it * 32 + r) * 1024 + spl * 512 +
                       (hp + 4 * sh) * 64 + scc * 8;
      GLDS(src, (char*)KsL[p] + c * 1024);
    }
#pragma unroll
    for (int i = 0; i < 2; ++i) {
      const int c = cw + i;
      const int sh = c >> 3, dg = c & 7;
      const int d = dg * 8 + sgrp;
      const int spl = scc >> 2, kc = scc & 3;
      const u16* src = vtg + (size_t)(b * 512 + (hp + 4 * sh) * 64 + d) * 2048 +
                       spl * 1024 + it * 32 + kc * 8;
      GLDS(src, (char*)VtL[p] + c * 1024);
    }
  };

  const u16* bT = biasT + ((size_t)(b * 8 + head) * 1024) * 1024 + q0 + q;

  stage(0, 0);

  for (int it = 0; it < 32; ++it) {
    const int p = it & 1;
    __syncthreads();  // drains staging of tile it (in flight a full iter)
    if (it + 1 < 32) stage(it + 1, p ^ 1);

    // issue current tile's bias loads now (consumed after S MFMA)
    u16 rb[8];
    {
      const u16* bt = bT + (size_t)(it * 32) * 1024;
#pragma unroll
      for (int kt = 0; kt < 2; ++kt)
#pragma unroll
        for (int r = 0; r < 4; ++r)
          rb[kt * 4 + r] = bt[(size_t)(kt * 16 + lg * 4 + r) * 1024];
    }

    // ---- S^T = K . Q^T (3-term split) ----
    const u16* Kb = KsL[p];
    f32x4 st[2] = {};
#pragma unroll
    for (int kt = 0; kt < 2; ++kt) {
      const int krow = kt * 16 + lq;
      const int rx = krow & 7;
#pragma unroll
      for (int ks = 0; ks < 2; ++ks) {
        const int phys = (ks * 4 + lg) ^ rx;
        const bf16x8 khi = *(const bf16x8*)(Kb + ((h * 2 + 0) * 32 + krow) * 64 + phys * 8);
        const bf16x8 klo = *(const bf16x8*)(Kb + ((h * 2 + 1) * 32 + krow) * 64 + phys * 8);
        st[kt] = MFMA(khi, Qf[ks][1], st[kt]);
        st[kt] = MFMA(klo, Qf[ks][0], st[kt]);
        st[kt] = MFMA(khi, Qf[ks][0], st[kt]);
      }
    }

    // ---- online softmax (q = lane col, k = regs) ----
    float sv[2][4];
    float mx = -1e30f;
#pragma unroll
    for (int kt = 0; kt < 2; ++kt)
#pragma unroll
      for (int r = 0; r < 4; ++r) {
        const float s = st[kt][r] + h2f(rb[kt * 4 + r]);
        sv[kt][r] = s;
        mx = fmaxf(mx, s);
      }
    mx = fmaxf(mx, __shfl_xor(mx, 16, 64));
    mx = fmaxf(mx, __shfl_xor(mx, 32, 64));
    const float mnew = fmaxf(m_run, mx);
    const float a = __expf(m_run - mnew);
    m_run = mnew;
    float pr[2][4], ps = 0.0f;
#pragma unroll
    for (int kt = 0; kt < 2; ++kt)
#pragma unroll
      for (int r = 0; r < 4; ++r) {
        pr[kt][r] = __expf(sv[kt][r] - mnew);
        ps += pr[kt][r];
      }
    ps += __shfl_xor(ps, 16, 64);
    ps += __shfl_xor(ps, 32, 64);
    l_run = l_run * a + ps;
#pragma unroll
    for (int dt = 0; dt < 4; ++dt) Ya[dt] *= a;
    if (h == 1) {
#pragma unroll
      for (int dt = 0; dt < 4; ++dt) Yb[dt] *= a;
    }

    // ---- P: D-layout -> B-operand frag via shuffles, split-bf16 ----
    const int srcA = lq + ((lg & 1) << 5);
    float pj[8];
#pragma unroll
    for (int r = 0; r < 4; ++r) {
      const float t0 = __shfl(pr[0][r], srcA);
      const float t1 = __shfl(pr[1][r], srcA);
      pj[r] = (lg >= 2) ? t1 : t0;
      const float u0 = __shfl(pr[0][r], srcA + 16);
      const float u1 = __shfl(pr[1][r], srcA + 16);
      pj[4 + r] = (lg >= 2) ? u1 : u0;
    }
    u16 phh[8], pll[8];
#pragma unroll
    for (int e = 0; e < 8; ++e) split2(pj[e], phh[e], pll[e]);
    const uint4 Hu = pack8(phh), Lu = pack8(pll);
    bf16x8 pbh, pbl;
    __builtin_memcpy(&pbh, &Hu, 16);
    __builtin_memcpy(&pbl, &Lu, 16);

    // ---- PV (full 64 d per wave) ----
    const u16* Vb = VtL[p];
    if (h == 0) {
#pragma unroll
      for (int dt = 0; dt < 4; ++dt) {
        const int d = dt * 16 + lq;
        const int dx = d & 7;
        const bf16x8 vh = *(const bf16x8*)(Vb + d * 64 + ((0 + lg) ^ dx) * 8);
        const bf16x8 vl = *(const bf16x8*)(Vb + d * 64 + ((4 + lg) ^ dx) * 8);
        Ya[dt] = MFMA(vh, pbl, Ya[dt]);
        Ya[dt] = MFMA(vl, pbh, Ya[dt]);
        Ya[dt] = MFMA(vh, pbh, Ya[dt]);
      }
    } else {
#pragma unroll
      for (int dt = 0; dt < 4; ++dt) {
        const int d = dt * 16 + lq;
        const int dx = d & 7;
        const bf16x8 v1h = *(const bf16x8*)(Vb + d * 64 + ((0 + lg) ^ dx) * 8);
        const bf16x8 v1l = *(const bf16x8*)(Vb + d * 64 + ((4 + lg) ^ dx) * 8);
        Yb[dt] = MFMA(v1h, pbl, Yb[dt]);
        Yb[dt] = MFMA(v1l, pbh, Yb[dt]);
        Yb[dt] = MFMA(v1h, pbh, Yb[dt]);
        const bf16x8 v2h = *(const bf16x8*)(Vb + (64 + d) * 64 + ((0 + lg) ^ dx) * 8);
        const bf16x8 v2l = *(const bf16x8*)(Vb + (64 + d) * 64 + ((4 + lg) ^ dx) * 8);
        Ya[dt] = MFMA(v2h, pbl, Ya[dt]);
        Ya[dt] = MFMA(v2l, pbh, Ya[dt]);
        Ya[dt] = MFMA(v2h, pbh, Ya[dt]);
      }
    }
  }

  // ---- epilogue: h1 publishes Y2 + l2 once; combine; split-bf16 out ----
  __syncthreads();
  float* y2x = (float*)VtL;  // [qs 4][lane 64][16] = 16 KB
  float* l2s = (float*)KsL;  // [qs*16 + lq]
  if (h == 1) {
    if (lane < 16) l2s[qs * 16 + lane] = l_run;
#pragma unroll
    for (int dt = 0; dt < 4; ++dt)
#pragma unroll
      for (int r = 0; r < 4; ++r)
        y2x[(qs * 64 + lane) * 16 + dt * 4 + r] = Yb[dt][r];
  }
  __syncthreads();
  if (h == 1) {
    const float inv2 = 1.0f / l_run;
#pragma unroll
    for (int dt = 0; dt < 4; ++dt) {
      u16 hh[4], ll[4];
#pragma unroll
      for (int r = 0; r < 4; ++r) split2(Ya[dt][r] * inv2, hh[r], ll[r]);
      u16* o = xo + qrow * 1024 + (hp + 4) * 64 + dt * 16 + lg * 4;
      *(uint2*)o = pack4(hh);
      *(uint2*)(o + 512) = pack4(ll);
    }
  } else {
    const float inv1 = 1.0f / l_run;
    const float inv2 = 1.0f / l2s[qs * 16 + lq];
    const float c1 = (1.0f + alpha) * inv1;
    const float c2 = alpha * lam_s * inv2;
#pragma unroll
    for (int dt = 0; dt < 4; ++dt) {
      u16 hh[4], ll[4];
#pragma unroll
      for (int r = 0; r < 4; ++r) {
        const float y2 = y2x[(qs * 64 + lane) * 16 + dt * 4 + r];
        split2(c1 * Ya[dt][r] - c2 * y2, hh[r], ll[r]);
      }
      u16* o = xo + qrow * 1024 + hp * 64 + dt * 16 + lg * 4;
      *(uint2*)o = pack4(hh);
      *(uint2*)(o + 512) = pack4(ll);
    }
  }
}

// =====================================================================
extern "C" void kernel_launch(void* const* d_in, const int* in_sizes, int n_in,
                              void* d_out, int out_size, void* d_ws, size_t ws_size,
                              hipStream_t stream) {
  const float* x_q   = (const float*)d_in[0];
  const float* x_kv  = (const float*)d_in[1];
  const int*   c_q   = (const int*)d_in[2];
  const int*   c_k   = (const int*)d_in[3];
  const float* alpha = (const float*)d_in[4];
  const float* Wq    = (const float*)d_in[5];
  const float* bq    = (const float*)d_in[6];
  const float* Wk    = (const float*)d_in[7];
  const float* bk    = (const float*)d_in[8];
  const float* Wv    = (const float*)d_in[9];
  const float* bv    = (const float*)d_in[10];
  const float* lq1   = (const float*)d_in[11];
  const float* lk1   = (const float*)d_in[12];
  const float* lq2   = (const float*)d_in[13];
  const float* lk2   = (const float*)d_in[14];
  const float* rpe   = (const float*)d_in[15];
  const float* Wp    = (const float*)d_in[16];
  const float* bp    = (const float*)d_in[17];

  // ws: w2[0,4) | q2[4,12) | k2[12,20) | xa[20,28) | biasT[28,92).
  // d_out: vt (written by V-GEMM) during attention, then final output.
  u16* w2    = (u16*)d_ws;
  u16* q2    = (u16*)((char*)d_ws + (4u << 20));
  u16* k2    = (u16*)((char*)d_ws + (12u << 20));
  u16* xa    = (u16*)((char*)d_ws + (20u << 20));
  u16* biasT = (u16*)((char*)d_ws + (28u << 20));
  u16* vt    = (u16*)d_out;

  split_w4<<<dim3(256, 4), 256, 0, stream>>>(Wq, Wk, Wv, Wp, w2);
  rpebuild<<<dim3(16, 64, 4), 256, 0, stream>>>(c_q, c_k, rpe, biasT);
  gemm_qkv<<<dim3(8, 64, 3), 256, 0, stream>>>(x_q, x_kv, w2, bq, bk, bv,
                                               q2, k2, vt);
  attn_mfma<<<dim3(16, 4, NB), 512, 0, stream>>>(
      q2, k2, vt, alpha, lq1, lk1, lq2, lk2, biasT, xa);
  gemm_out<<<dim3(8, 64), 256, 0, stream>>>(xa, w2 + 3 * 524288, bp,
                                            (float*)d_out);
}

// Round 9
// 230.334 us; speedup vs baseline: 2.0160x; 1.1268x over previous
//
#include <hip/hip_runtime.h>
#include <cstddef>
#include <cstdint>

#define DIM   512
#define NSEQ  1024
#define NB    4

typedef unsigned short u16;
typedef short bf16x8 __attribute__((ext_vector_type(8)));
typedef _Float16 half8v __attribute__((ext_vector_type(8)));
typedef float f32x4  __attribute__((ext_vector_type(4)));

#define MFMA(a, b, c)  __builtin_amdgcn_mfma_f32_16x16x32_bf16(a, b, c, 0, 0, 0)
#define MFMAH(a, b, c) __builtin_amdgcn_mfma_f32_16x16x32_f16(a, b, c, 0, 0, 0)

// RNE fp32 -> bf16 split: x ~= hi + lo (error ~2^-18 * |x|)
__device__ inline void split2(float x, u16& h, u16& l) {
  unsigned u = __float_as_uint(x);
  unsigned hb = (u + 0x7fffu + ((u >> 16) & 1u)) >> 16;
  float fh = __uint_as_float(hb << 16);
  float r = x - fh;
  unsigned v = __float_as_uint(r);
  unsigned lb = (v + 0x7fffu + ((v >> 16) & 1u)) >> 16;
  h = (u16)hb; l = (u16)lb;
}

__device__ inline uint2 pack4(const u16 a[4]) {
  return make_uint2((unsigned)a[0] | ((unsigned)a[1] << 16),
                    (unsigned)a[2] | ((unsigned)a[3] << 16));
}

__device__ inline uint4 pack8(const u16 a[8]) {
  return make_uint4((unsigned)a[0] | ((unsigned)a[1] << 16),
                    (unsigned)a[2] | ((unsigned)a[3] << 16),
                    (unsigned)a[4] | ((unsigned)a[5] << 16),
                    (unsigned)a[6] | ((unsigned)a[7] << 16));
}

__device__ inline u16 f2h(float x) {
  _Float16 h = (_Float16)x;
  u16 r; __builtin_memcpy(&r, &h, 2);
  return r;
}
__device__ inline float h2f(u16 b) {
  _Float16 h; __builtin_memcpy(&h, &b, 2);
  return (float)h;
}
// pack two fp32 -> fp16x2 in a u32 (RNE)
__device__ inline unsigned pkh2(float a, float b) {
  return (unsigned)f2h(a) | ((unsigned)f2h(b) << 16);
}

// fp32 [rows][512] -> u16 [rows][1024] (hi plane | lo plane)
__global__ __launch_bounds__(256) void split_w4(
    const float* __restrict__ w0, const float* __restrict__ w1,
    const float* __restrict__ w2, const float* __restrict__ w3,
    u16* __restrict__ out) {
  const int y = blockIdx.y;
  const float* src = (y == 0) ? w0 : (y == 1) ? w1 : (y == 2) ? w2 : w3;
  u16* o0 = out + (size_t)y * 524288;
  const int e = (blockIdx.x * 256 + threadIdx.x) * 4;
  const int m = e >> 9, c = e & 511;
  const float4 v = *(const float4*)(src + e);
  u16 h[4], l[4];
  split2(v.x, h[0], l[0]); split2(v.y, h[1], l[1]);
  split2(v.z, h[2], l[2]); split2(v.w, h[3], l[3]);
  u16* o = o0 + (size_t)m * 1024 + c;
  *(uint2*)o = pack4(h);
  *(uint2*)(o + 512) = pack4(l);
}

#define GLDS(g, l)                                                        \
  __builtin_amdgcn_global_load_lds(                                       \
      (const __attribute__((address_space(1))) void*)(g),                 \
      (__attribute__((address_space(3))) void*)(l), 16, 0, 0)

// =====================================================================
// Dense RPE bias: biasT[b][head][k][q] fp16 (validated r7).
// =====================================================================
__global__ __launch_bounds__(256) void rpebuild(
    const int* __restrict__ cq, const int* __restrict__ ck,
    const float* __restrict__ rpe, u16* __restrict__ biasT) {
  __shared__ u16 Ts[8 * 16 * 64];  // [h][k][q] 16 KB
  const int t = threadIdx.x;
  const int q0 = blockIdx.x * 64, k0 = blockIdx.y * 16, b = blockIdx.z;
  const int qn = t & 63, kb = t >> 6;
  const int2 cqv = ((const int2*)cq)[b * NSEQ + q0 + qn];
#pragma unroll
  for (int j = 0; j < 4; ++j) {
    const int k = kb * 4 + j;
    const int2 ckv = ((const int2*)ck)[b * NSEQ + k0 + k];
    const int r0 = min(max(cqv.x - ckv.x + 128, 0), 256);
    const int r1 = min(max(cqv.y - ckv.y + 128, 0), 256);
    const float* rp = rpe + (size_t)(r0 * 257 + r1) * 8;
    const float4 f0 = *(const float4*)rp;
    const float4 f1 = *(const float4*)(rp + 4);
    u16* dst = Ts + k * 64 + qn;
    dst[0 * 1024] = f2h(f0.x); dst[1 * 1024] = f2h(f0.y);
    dst[2 * 1024] = f2h(f0.z); dst[3 * 1024] = f2h(f0.w);
    dst[4 * 1024] = f2h(f1.x); dst[5 * 1024] = f2h(f1.y);
    dst[6 * 1024] = f2h(f1.z); dst[7 * 1024] = f2h(f1.w);
  }
  __syncthreads();
#pragma unroll
  for (int i = 0; i < 4; ++i) {
    const int e = i * 256 + t;
    const int row = e >> 3, c8 = e & 7;  // row = h*16 + k
    const int hh = row >> 4, k = row & 15;
    const uint4 v = *(const uint4*)(Ts + row * 64 + c8 * 8);
    *(uint4*)(biasT + ((size_t)(b * 8 + hh) * 1024 + k0 + k) * 1024 +
              q0 + c8 * 8) = v;
  }
}

// =====================================================================
// Split-bf16 MFMA GEMM body (core validated r2-r8).
// OUT_MODE: 0 = fp32 [m][512]; 3 = fp16 [m][512] (scaled);
//           4 = fp16 vt layout [(b*512+col)][1024 k] — V GEMM.
// =====================================================================
template <int A_SPLIT, int OUT_MODE>
__device__ __forceinline__ void gemm_body(
    u16* __restrict__ Ah, u16* __restrict__ Al,
    u16* __restrict__ Bh, u16* __restrict__ Bl,
    const void* __restrict__ Ap, const u16* __restrict__ B2,
    const float* __restrict__ bias, void* __restrict__ outp,
    float scale, int m0, int n0) {
  const int tid = threadIdx.x;
  const int lane = tid & 63, w = tid >> 6;
  const int wm = (w & 1) * 32, wn = (w >> 1) * 32;

  const int sr  = w * 16 + (lane >> 3);
  const int scg = (lane & 7) ^ (sr & 7);
  const size_t bR = (size_t)(n0 + sr) * 1024 + scg * 8;
  const u16* gBh0 = B2 + bR;        const u16* gBh1 = B2 + bR + 8192;
  const u16* gBl0 = B2 + bR + 512;  const u16* gBl1 = B2 + bR + 8704;
  char* lBh = (char*)Bh + w * 2048; char* lBl = (char*)Bl + w * 2048;

  const u16* gAh0 = nullptr; const u16* gAh1 = nullptr;
  const u16* gAl0 = nullptr; const u16* gAl1 = nullptr;
  char* lAh = (char*)Ah + w * 2048; char* lAl = (char*)Al + w * 2048;
  const float* Af = nullptr;
  int arow = 0, apos0 = 0, apos1 = 0;
  if (A_SPLIT) {
    const size_t aR = (size_t)(m0 + sr) * 1024 + scg * 8;
    gAh0 = (const u16*)Ap + aR; gAh1 = gAh0 + 8192;
    gAl0 = gAh0 + 512;          gAl1 = gAh0 + 8704;
  } else {
    arow = tid >> 2;
    const int acg = tid & 3;
    Af = (const float*)Ap + (size_t)(m0 + arow) * 512 + acg * 8;
    apos0 = (acg ^ (arow & 7)) * 8;
    apos1 = ((acg + 4) ^ (arow & 7)) * 8;
  }

  const int fr = lane & 15, kq = lane >> 4, fx = lane & 7;
  int aoff[2][2], boff[2][2];
#pragma unroll
  for (int s = 0; s < 2; ++s)
#pragma unroll
    for (int t = 0; t < 2; ++t) {
      aoff[s][t] = (wm + t * 16 + fr) * 64 + (((s * 4 + kq) ^ fx)) * 8;
      boff[s][t] = (wn + t * 16 + fr) * 64 + (((s * 4 + kq) ^ fx)) * 8;
    }

  f32x4 acc[2][2] = {};
  for (int k0 = 0; k0 < 512; k0 += 64) {
    float4 f0, f1, f2, f3;
    if (!A_SPLIT) {
      f0 = *(const float4*)(Af + k0);
      f1 = *(const float4*)(Af + k0 + 4);
      f2 = *(const float4*)(Af + k0 + 32);
      f3 = *(const float4*)(Af + k0 + 36);
    }
    __syncthreads();
    GLDS(gBh0 + k0, lBh); GLDS(gBh1 + k0, lBh + 1024);
    GLDS(gBl0 + k0, lBl); GLDS(gBl1 + k0, lBl + 1024);
    if (A_SPLIT) {
      GLDS(gAh0 + k0, lAh); GLDS(gAh1 + k0, lAh + 1024);
      GLDS(gAl0 + k0, lAl); GLDS(gAl1 + k0, lAl + 1024);
    } else {
      u16 h8[8], l8[8];
      split2(f0.x, h8[0], l8[0]); split2(f0.y, h8[1], l8[1]);
      split2(f0.z, h8[2], l8[2]); split2(f0.w, h8[3], l8[3]);
      split2(f1.x, h8[4], l8[4]); split2(f1.y, h8[5], l8[5]);
      split2(f1.z, h8[6], l8[6]); split2(f1.w, h8[7], l8[7]);
      *(uint4*)(Ah + arow * 64 + apos0) = pack8(h8);
      *(uint4*)(Al + arow * 64 + apos0) = pack8(l8);
      split2(f2.x, h8[0], l8[0]); split2(f2.y, h8[1], l8[1]);
      split2(f2.z, h8[2], l8[2]); split2(f2.w, h8[3], l8[3]);
      split2(f3.x, h8[4], l8[4]); split2(f3.y, h8[5], l8[5]);
      split2(f3.z, h8[6], l8[6]); split2(f3.w, h8[7], l8[7]);
      *(uint4*)(Ah + arow * 64 + apos1) = pack8(h8);
      *(uint4*)(Al + arow * 64 + apos1) = pack8(l8);
    }
    __syncthreads();
#pragma unroll
    for (int s = 0; s < 2; ++s) {
      bf16x8 ah[2], al[2], bh[2], bl[2];
#pragma unroll
      for (int t = 0; t < 2; ++t) {
        ah[t] = *(const bf16x8*)(Ah + aoff[s][t]);
        al[t] = *(const bf16x8*)(Al + aoff[s][t]);
        bh[t] = *(const bf16x8*)(Bh + boff[s][t]);
        bl[t] = *(const bf16x8*)(Bl + boff[s][t]);
      }
#pragma unroll
      for (int i = 0; i < 2; ++i)
#pragma unroll
        for (int j = 0; j < 2; ++j) {
          acc[i][j] = MFMA(al[i], bh[j], acc[i][j]);
          acc[i][j] = MFMA(ah[i], bl[j], acc[i][j]);
          acc[i][j] = MFMA(ah[i], bh[j], acc[i][j]);
        }
    }
  }

  const int er = (lane >> 4) * 4, ec = lane & 15;
#pragma unroll
  for (int i = 0; i < 2; ++i)
#pragma unroll
    for (int j = 0; j < 2; ++j) {
      const int row = m0 + wm + i * 16 + er;
      const int col = n0 + wn + j * 16 + ec;
      const float bv = bias[col];
      if (OUT_MODE == 4) {
        u16 hf[4];
#pragma unroll
        for (int r = 0; r < 4; ++r) hf[r] = f2h(acc[i][j][r] + bv);
        const int bb = row >> 10, kk = row & 1023;
        *(uint2*)((u16*)outp + ((size_t)(bb * 512 + col)) * 1024 + kk) =
            pack4(hf);
      } else {
#pragma unroll
        for (int r = 0; r < 4; ++r) {
          const float v = (acc[i][j][r] + bv) * scale;
          if (OUT_MODE == 3) {
            ((u16*)outp)[(size_t)(row + r) * 512 + col] = f2h(v);
          } else {
            ((float*)outp)[(size_t)(row + r) * 512 + col] = v;
          }
        }
      }
    }
}

// Fused Q/K/V projections: fp16 outputs (q/k row-major, v transposed).
__global__ __launch_bounds__(256) void gemm_qkv(
    const float* __restrict__ xq, const float* __restrict__ xkv,
    const u16* __restrict__ w2, const float* __restrict__ bq,
    const float* __restrict__ bk, const float* __restrict__ bv,
    u16* __restrict__ q2f, u16* __restrict__ k2f, u16* __restrict__ vtf) {
  __shared__ __align__(16) u16 Ah[4096], Al[4096], Bh[4096], Bl[4096];
  const int z = blockIdx.z;
  const float* A = (z == 0) ? xq : xkv;
  const u16* B = w2 + (size_t)z * 524288;
  const int m0 = blockIdx.y * 64, n0 = blockIdx.x * 64;
  if (z == 2) {
    gemm_body<0, 4>(Ah, Al, Bh, Bl, A, B, bv, vtf, 1.0f, m0, n0);
  } else if (z == 1) {
    gemm_body<0, 3>(Ah, Al, Bh, Bl, A, B, bk, k2f, 1.0f, m0, n0);
  } else {
    gemm_body<0, 3>(Ah, Al, Bh, Bl, A, B, bq, q2f, 0.125f, m0, n0);
  }
}

__global__ __launch_bounds__(256) void gemm_out(
    const u16* __restrict__ xa2, const u16* __restrict__ w2p,
    const float* __restrict__ bp, float* __restrict__ out) {
  __shared__ __align__(16) u16 Ah[4096], Al[4096], Bh[4096], Bl[4096];
  gemm_body<1, 0>(Ah, Al, Bh, Bl, xa2, w2p, bp, out, 1.0f,
                  blockIdx.y * 64, blockIdx.x * 64);
}

// =====================================================================
// fp16 MFMA differential flash attention, v5.
// All attention mats single-plane fp16 (error analysis: score err
// ~1.3e-4, xa err ~3e-4 — inside the 8e-4 threshold). S: 4 MFMA,
// PV: 4 (h0) / 8 (h1) per wave-iter. LDS: K 2x8KB + Vt 2x8KB = 32.3 KB
// -> 4 blocks/CU x 4 waves = 4 waves/SIMD (2x round 8).
// Grid (32 qtiles, 4 hp, NB), 256 thr = 4 waves (h, qs). One barrier
// per K-iter, prefetch right after it (r6-validated). Dense fp16 bias.
// K LDS: [h*32+k][64d], XOR-8 chunk swizzle; Vt LDS: [d][h0 32k|h1 32k].
// =====================================================================
__global__ __launch_bounds__(256) void attn_f16(
    const u16* __restrict__ q2f, const u16* __restrict__ k2f,
    const u16* __restrict__ vtf, const float* __restrict__ amap,
    const float* __restrict__ lq1, const float* __restrict__ lk1,
    const float* __restrict__ lq2, const float* __restrict__ lk2,
    const u16* __restrict__ biasT, u16* __restrict__ xo) {
  __shared__ __align__(16) u16 KsL[2][4096];  // [buf][(h*32+k)*64 + d]
  __shared__ __align__(16) u16 VtL[2][4096];  // [buf][d*64 + (h*4+kc)^]
  __shared__ float lam_s;

  const int tid = threadIdx.x;
  const int lane = tid & 63, w = tid >> 6;
  const int h = w >> 1, qs = w & 1;
  const int hp = blockIdx.y, b = blockIdx.z;
  const int q0 = blockIdx.x * 32;
  const int head = hp + 4 * h;
  const int lq = lane & 15, lg = lane >> 4;
  const int q = qs * 16 + lq;
  const size_t qrow = (size_t)(b * NSEQ + q0 + q);

  if (tid < 64) {
    float p1 = lq1[hp * 64 + tid] * lk1[hp * 64 + tid];
    float p2 = lq2[hp * 64 + tid] * lk2[hp * 64 + tid];
#pragma unroll
    for (int m = 32; m >= 1; m >>= 1) {
      p1 += __shfl_xor(p1, m, 64);
      p2 += __shfl_xor(p2, m, 64);
    }
    if (tid == 0) lam_s = __expf(p1) - __expf(p2) + 0.8f;
  }

  const float alpha = amap[qrow];

  // Q A-operand frags (q2f pre-scaled by 1/8): ks = 32-d halves
  half8v Qf[2];
#pragma unroll
  for (int ks = 0; ks < 2; ++ks)
    Qf[ks] = *(const half8v*)(q2f + qrow * 512 + head * 64 + ks * 32 + lg * 8);

  f32x4 Ya[4] = {};  // h0: Y1 ; h1: Y3
  f32x4 Yb[4] = {};  // h1: Y2
  float m_run = -1e30f, l_run = 0.0f;

  const int lr = lane >> 3, pc = lane & 7;
  const int lc = pc ^ lr;             // logical chunk from phys (XOR-8)
  const int cw = w * 2;               // 2 K-chunks + 2 Vt-chunks per wave

  auto stage = [&](int it, int p) {
#pragma unroll
    for (int i = 0; i < 2; ++i) {
      const int c = cw + i;                       // K chunk 0..7
      const int row = c * 8 + lr;                 // h*32 + k
      const int sh = row >> 5, k = row & 31;
      const u16* src = k2f + (size_t)(b * NSEQ + it * 32 + k) * 512 +
                       (hp + 4 * sh) * 64 + lc * 8;
      GLDS(src, (char*)KsL[p] + c * 1024);
    }
#pragma unroll
    for (int i = 0; i < 2; ++i) {
      const int c = cw + i;                       // Vt chunk 0..7
      const int d = c * 8 + lr;
      const int hv = lc >> 2, kc = lc & 3;
      const u16* src = vtf + (size_t)(b * 512 + (hp + 4 * hv) * 64 + d) * 1024 +
                       it * 32 + kc * 8;
      GLDS(src, (char*)VtL[p] + c * 1024);
    }
  };

  const u16* bT = biasT + ((size_t)(b * 8 + head) << 20) + q0 + q;

  stage(0, 0);

  for (int it = 0; it < 32; ++it) {
    const int p = it & 1;
    __syncthreads();  // drains staging of tile it (in flight a full iter)
    if (it + 1 < 32) stage(it + 1, p ^ 1);

    // bias loads for this tile (consumed after S MFMA)
    u16 rb[8];
    {
      const u16* bt = bT + (size_t)(it * 32) * 1024;
#pragma unroll
      for (int kt = 0; kt < 2; ++kt)
#pragma unroll
        for (int r = 0; r < 4; ++r)
          rb[kt * 4 + r] = bt[(size_t)(kt * 16 + lg * 4 + r) * 1024];
    }

    // ---- S^T = K . Q^T (fp16, single product) ----
    const u16* Kb = KsL[p];
    f32x4 st[2] = {};
#pragma unroll
    for (int kt = 0; kt < 2; ++kt) {
      const int krow = kt * 16 + lq;
      const int rx = krow & 7;
#pragma unroll
      for (int ks = 0; ks < 2; ++ks) {
        const int phys = (ks * 4 + lg) ^ rx;
        const half8v kf = *(const half8v*)(Kb + (h * 32 + krow) * 64 + phys * 8);
        st[kt] = MFMAH(kf, Qf[ks], st[kt]);
      }
    }

    // ---- online softmax (q = lane col, k = regs) ----
    float sv[2][4];
    float mx = -1e30f;
#pragma unroll
    for (int kt = 0; kt < 2; ++kt)
#pragma unroll
      for (int r = 0; r < 4; ++r) {
        const float s = st[kt][r] + h2f(rb[kt * 4 + r]);
        sv[kt][r] = s;
        mx = fmaxf(mx, s);
      }
    mx = fmaxf(mx, __shfl_xor(mx, 16, 64));
    mx = fmaxf(mx, __shfl_xor(mx, 32, 64));
    const float mnew = fmaxf(m_run, mx);
    const float a = __expf(m_run - mnew);
    m_run = mnew;
    float pr[2][4], ps = 0.0f;
#pragma unroll
    for (int kt = 0; kt < 2; ++kt)
#pragma unroll
      for (int r = 0; r < 4; ++r) {
        pr[kt][r] = __expf(sv[kt][r] - mnew);
        ps += pr[kt][r];
      }
    ps += __shfl_xor(ps, 16, 64);
    ps += __shfl_xor(ps, 32, 64);
    l_run = l_run * a + ps;
#pragma unroll
    for (int dt = 0; dt < 4; ++dt) Ya[dt] *= a;
    if (h == 1) {
#pragma unroll
      for (int dt = 0; dt < 4; ++dt) Yb[dt] *= a;
    }

    // ---- P: D-layout -> B-operand fp16 frag (pack, then 8 shuffles) ----
    const unsigned a0 = pkh2(pr[0][0], pr[0][1]);
    const unsigned a1 = pkh2(pr[0][2], pr[0][3]);
    const unsigned b0 = pkh2(pr[1][0], pr[1][1]);
    const unsigned b1 = pkh2(pr[1][2], pr[1][3]);
    const int srcA = lq + ((lg & 1) << 5);
    const unsigned A0 = __shfl((int)a0, srcA),      A1 = __shfl((int)a1, srcA);
    const unsigned B0 = __shfl((int)b0, srcA),      B1 = __shfl((int)b1, srcA);
    const unsigned C0 = __shfl((int)a0, srcA + 16), C1 = __shfl((int)a1, srcA + 16);
    const unsigned D0 = __shfl((int)b0, srcA + 16), D1 = __shfl((int)b1, srcA + 16);
    const bool t2 = lg >= 2;
    const uint4 Pu = make_uint4(t2 ? B0 : A0, t2 ? B1 : A1,
                                t2 ? D0 : C0, t2 ? D1 : C1);
    half8v pb;
    __builtin_memcpy(&pb, &Pu, 16);

    // ---- PV (full 64 d per wave) ----
    const u16* Vb = VtL[p];
    if (h == 0) {
#pragma unroll
      for (int dt = 0; dt < 4; ++dt) {
        const int d = dt * 16 + lq;
        const half8v v1 = *(const half8v*)(Vb + d * 64 + ((lg ^ (d & 7))) * 8);
        Ya[dt] = MFMAH(v1, pb, Ya[dt]);
      }
    } else {
#pragma unroll
      for (int dt = 0; dt < 4; ++dt) {
        const int d = dt * 16 + lq;
        const int dx = d & 7;
        const half8v v1 = *(const half8v*)(Vb + d * 64 + ((lg ^ dx)) * 8);
        Yb[dt] = MFMAH(v1, pb, Yb[dt]);
        const half8v v2 = *(const half8v*)(Vb + d * 64 + (((4 + lg) ^ dx)) * 8);
        Ya[dt] = MFMAH(v2, pb, Ya[dt]);
      }
    }
  }

  // ---- epilogue: h1 publishes Y2 + l2 once; combine; split-bf16 out ----
  __syncthreads();
  float* y2x = (float*)VtL;  // [qs 2][lane 64][16] = 8 KB
  float* l2s = (float*)KsL;  // [qs*16 + lq]
  if (h == 1) {
    if (lane < 16) l2s[qs * 16 + lane] = l_run;
#pragma unroll
    for (int dt = 0; dt < 4; ++dt)
#pragma unroll
      for (int r = 0; r < 4; ++r)
        y2x[(qs * 64 + lane) * 16 + dt * 4 + r] = Yb[dt][r];
  }
  __syncthreads();
  if (h == 1) {
    const float inv2 = 1.0f / l_run;
#pragma unroll
    for (int dt = 0; dt < 4; ++dt) {
      u16 hh[4], ll[4];
#pragma unroll
      for (int r = 0; r < 4; ++r) split2(Ya[dt][r] * inv2, hh[r], ll[r]);
      u16* o = xo + qrow * 1024 + (hp + 4) * 64 + dt * 16 + lg * 4;
      *(uint2*)o = pack4(hh);
      *(uint2*)(o + 512) = pack4(ll);
    }
  } else {
    const float inv1 = 1.0f / l_run;
    const float inv2 = 1.0f / l2s[qs * 16 + lq];
    const float c1 = (1.0f + alpha) * inv1;
    const float c2 = alpha * lam_s * inv2;
#pragma unroll
    for (int dt = 0; dt < 4; ++dt) {
      u16 hh[4], ll[4];
#pragma unroll
      for (int r = 0; r < 4; ++r) {
        const float y2 = y2x[(qs * 64 + lane) * 16 + dt * 4 + r];
        split2(c1 * Ya[dt][r] - c2 * y2, hh[r], ll[r]);
      }
      u16* o = xo + qrow * 1024 + hp * 64 + dt * 16 + lg * 4;
      *(uint2*)o = pack4(hh);
      *(uint2*)(o + 512) = pack4(ll);
    }
  }
}

// =====================================================================
extern "C" void kernel_launch(void* const* d_in, const int* in_sizes, int n_in,
                              void* d_out, int out_size, void* d_ws, size_t ws_size,
                              hipStream_t stream) {
  const float* x_q   = (const float*)d_in[0];
  const float* x_kv  = (const float*)d_in[1];
  const int*   c_q   = (const int*)d_in[2];
  const int*   c_k   = (const int*)d_in[3];
  const float* alpha = (const float*)d_in[4];
  const float* Wq    = (const float*)d_in[5];
  const float* bq    = (const float*)d_in[6];
  const float* Wk    = (const float*)d_in[7];
  const float* bk    = (const float*)d_in[8];
  const float* Wv    = (const float*)d_in[9];
  const float* bv    = (const float*)d_in[10];
  const float* lq1   = (const float*)d_in[11];
  const float* lk1   = (const float*)d_in[12];
  const float* lq2   = (const float*)d_in[13];
  const float* lk2   = (const float*)d_in[14];
  const float* rpe   = (const float*)d_in[15];
  const float* Wp    = (const float*)d_in[16];
  const float* bp    = (const float*)d_in[17];

  // ws: w2[0,4) | q2f[4,8) | k2f[8,12) | vtf[12,16) | xa[16,24)
  //     | biasT[28,92). All within the 92 MB proven in r7/r8.
  u16* w2    = (u16*)d_ws;
  u16* q2f   = (u16*)((char*)d_ws + (4u << 20));
  u16* k2f   = (u16*)((char*)d_ws + (8u << 20));
  u16* vtf   = (u16*)((char*)d_ws + (12u << 20));
  u16* xa    = (u16*)((char*)d_ws + (16u << 20));
  u16* biasT = (u16*)((char*)d_ws + (28u << 20));

  split_w4<<<dim3(256, 4), 256, 0, stream>>>(Wq, Wk, Wv, Wp, w2);
  rpebuild<<<dim3(16, 64, 4), 256, 0, stream>>>(c_q, c_k, rpe, biasT);
  gemm_qkv<<<dim3(8, 64, 3), 256, 0, stream>>>(x_q, x_kv, w2, bq, bk, bv,
                                               q2f, k2f, vtf);
  attn_f16<<<dim3(32, 4, NB), 256, 0, stream>>>(
      q2f, k2f, vtf, alpha, lq1, lk1, lq2, lk2, biasT, xa);
  gemm_out<<<dim3(8, 64), 256, 0, stream>>>(xa, w2 + 3 * 524288, bp,
                                            (float*)d_out);
}